// Round 1
// baseline (1397.800 us; speedup 1.0000x reference)
//
#include <hip/hip_runtime.h>

#define H 128
#define ED 32
#define NLBL 256
#define NNODE_LBL 4096
#define LAYERS 3
#define BN 128         // nodes per block in matmul kernels
#define ZS 132         // padded LDS stride for transposed z tile (16B-aligned, bank-spread)

static __device__ __forceinline__ float relu_f(float x) { return fmaxf(x, 0.f); }

#define TWO48F 281474976710655.0f

// ---------------- edge feature path (256 distinct labels only) ----------------

__global__ void edge_proj_kernel(const float* __restrict__ emb,
                                 const float* __restrict__ Pe1, const float* __restrict__ be1,
                                 const float* __restrict__ Pe2, const float* __restrict__ be2,
                                 float* __restrict__ e_proj) {
    int a = blockIdx.x, d = threadIdx.x;   // block per label, 32 threads
    __shared__ float t[ED];
    float acc = be1[d];
    for (int k = 0; k < ED; ++k) acc = fmaf(emb[a * ED + k], Pe1[k * ED + d], acc);
    t[d] = fmaxf(acc, 0.f);
    __syncthreads();
    float acc2 = be2[d];
    for (int k = 0; k < ED; ++k) acc2 = fmaf(t[k], Pe2[k * ED + d], acc2);
    e_proj[a * ED + d] = acc2;
}

__global__ void el_tab_kernel(const float* __restrict__ e_proj,
                              const float* __restrict__ W_lin, const float* __restrict__ b_lin,
                              float* __restrict__ el_tab) {
    int a = blockIdx.x, l = blockIdx.y, k = threadIdx.x;  // 128 threads
    float acc = b_lin[l * H + k];
    for (int d = 0; d < ED; ++d)
        acc = fmaf(e_proj[a * ED + d], W_lin[(l * ED + d) * H + k], acc);
    el_tab[((size_t)l * NLBL + a) * H + k] = acc;
}

// ---------------- CSR build (histogram -> scan -> scatter) ----------------

__global__ void hist_kernel(const int* __restrict__ dst, int E, int* __restrict__ deg) {
    int e = blockIdx.x * blockDim.x + threadIdx.x;
    if (e < E) atomicAdd(&deg[dst[e]], 1);
}

__global__ void scan_block_sums(const int* __restrict__ deg, int n, int* __restrict__ bsum) {
    __shared__ int s[1024];
    int i = blockIdx.x * 1024 + threadIdx.x;
    s[threadIdx.x] = (i < n) ? deg[i] : 0;
    __syncthreads();
    for (int off = 512; off > 0; off >>= 1) {
        if (threadIdx.x < off) s[threadIdx.x] += s[threadIdx.x + off];
        __syncthreads();
    }
    if (threadIdx.x == 0) bsum[blockIdx.x] = s[0];
}

__global__ void scan_bsum(int* __restrict__ bsum, int nb, int* __restrict__ total_out) {
    if (threadIdx.x == 0) {
        int run = 0;
        for (int b = 0; b < nb; ++b) { int v = bsum[b]; bsum[b] = run; run += v; }
        *total_out = run;   // rowptr[N] = E
    }
}

__global__ void scan_final(const int* __restrict__ deg, int n,
                           const int* __restrict__ bsum, int* __restrict__ rowptr) {
    __shared__ int s[1024];
    int i = blockIdx.x * 1024 + threadIdx.x;
    int v = (i < n) ? deg[i] : 0;
    s[threadIdx.x] = v;
    __syncthreads();
    for (int off = 1; off < 1024; off <<= 1) {
        int add = (threadIdx.x >= off) ? s[threadIdx.x - off] : 0;
        __syncthreads();
        s[threadIdx.x] += add;
        __syncthreads();
    }
    if (i < n) rowptr[i] = bsum[blockIdx.x] + s[threadIdx.x] - v;  // exclusive
}

__global__ void scatter_kernel(const int* __restrict__ src, const int* __restrict__ dst,
                               const int* __restrict__ attr, int E,
                               const int* __restrict__ rowptr, int* __restrict__ cursor,
                               int* __restrict__ sorted) {
    int e = blockIdx.x * blockDim.x + threadIdx.x;
    if (e < E) {
        int d = dst[e];
        int pos = rowptr[d] + atomicAdd(&cursor[d], 1);
        sorted[pos] = src[e] | (attr[e] << 17);   // N < 2^17, attr < 2^8
    }
}

// ---------------- per-node aggregation: z = h + sum relu(h[src] + el[attr]) ----------------

__global__ __launch_bounds__(256) void gather_kernel(
    const float* __restrict__ h, const int* __restrict__ rowptr,
    const int* __restrict__ sorted, const float* __restrict__ el_tab_l,
    int n, float* __restrict__ z) {
    int wave = threadIdx.x >> 6;
    int lane = threadIdx.x & 63;
    int i = blockIdx.x * 4 + wave;
    if (i >= n) return;
    int beg = rowptr[i], end = rowptr[i + 1];
    const float2* h2 = (const float2*)h;
    const float2* e2 = (const float2*)el_tab_l;
    float accx = 0.f, accy = 0.f;
    for (int e = beg; e < end; ++e) {
        int p = sorted[e];
        int s = p & 131071;
        int a = p >> 17;
        float2 hv = h2[(size_t)s * 64 + lane];
        float2 ev = e2[(size_t)a * 64 + lane];
        accx += fmaxf(hv.x + ev.x, 0.f);
        accy += fmaxf(hv.y + ev.y, 0.f);
    }
    float2 hi = h2[(size_t)i * 64 + lane];
    float2 o; o.x = hi.x + accx; o.y = hi.y + accy;
    ((float2*)z)[(size_t)i * 64 + lane] = o;
}

// ---------------- fused 2-layer MLP: h = relu(relu(z@Wa+ba)@Wb+bb) ----------------
// 128-node tile; z staged transposed in LDS (sZ[k][node], stride ZS); weights staged
// in 32KB halves. Thread micro-tile: 8 nodes x 8 cols, split 4+4 at distance 64 so
// every ds_read_b128 is a 16-lane-consecutive (conflict-free) or broadcast pattern.

__global__ __launch_bounds__(256) void mlp_kernel(
    const float* __restrict__ z,
    const float* __restrict__ Wa, const float* __restrict__ ba,
    const float* __restrict__ Wb, const float* __restrict__ bb,
    int n, float* __restrict__ h) {
    __shared__ __align__(16) float sZ[H * ZS];
    __shared__ __align__(16) float sW[64 * H];
    const int t = threadIdx.x;
    const int n0 = blockIdx.x * BN;
    const int cg = t & 15, ng = t >> 4;
    const int c0 = 4 * cg, nA = 4 * ng;

    // stage z tile transposed: sZ[k*ZS + nn] = z[(n0+nn)*H + k]
    for (int idx = t; idx < BN * H; idx += 256) {
        int nn = idx >> 7, k = idx & 127;
        int node = n0 + nn;
        sZ[k * ZS + nn] = (node < n) ? z[(size_t)node * H + k] : 0.f;
    }

    float acc[64];
    {
        const float4 b0 = *(const float4*)&ba[c0];
        const float4 b1 = *(const float4*)&ba[64 + c0];
#pragma unroll
        for (int j = 0; j < 8; ++j) {
            acc[j * 8 + 0] = b0.x; acc[j * 8 + 1] = b0.y; acc[j * 8 + 2] = b0.z; acc[j * 8 + 3] = b0.w;
            acc[j * 8 + 4] = b1.x; acc[j * 8 + 5] = b1.y; acc[j * 8 + 6] = b1.z; acc[j * 8 + 7] = b1.w;
        }
    }

    // ---- matmul 1: T = relu(z @ Wa + ba) ----
#pragma unroll 1
    for (int hh = 0; hh < 2; ++hh) {
        __syncthreads();
        for (int i = t; i < 64 * H; i += 256) sW[i] = Wa[hh * 64 * H + i];
        __syncthreads();
#pragma unroll 2
        for (int k2 = 0; k2 < 64; ++k2) {
            int k = hh * 64 + k2;
            const float4 w0 = *(const float4*)&sW[k2 * H + c0];
            const float4 w1 = *(const float4*)&sW[k2 * H + 64 + c0];
            const float4 z0 = *(const float4*)&sZ[k * ZS + nA];
            const float4 z1 = *(const float4*)&sZ[k * ZS + 64 + nA];
            float zz[8] = {z0.x, z0.y, z0.z, z0.w, z1.x, z1.y, z1.z, z1.w};
            float ww[8] = {w0.x, w0.y, w0.z, w0.w, w1.x, w1.y, w1.z, w1.w};
#pragma unroll
            for (int j = 0; j < 8; ++j)
#pragma unroll
                for (int c = 0; c < 8; ++c)
                    acc[j * 8 + c] = fmaf(zz[j], ww[c], acc[j * 8 + c]);
        }
    }

    __syncthreads();  // all reads of sZ done; safe to overwrite with T
    // write T (with relu) transposed: sZ[col*ZS + node]
#pragma unroll
    for (int c = 0; c < 8; ++c) {
        int col = (c < 4) ? (c0 + c) : (64 + c0 + (c - 4));
        float4 v0 = make_float4(relu_f(acc[0 * 8 + c]), relu_f(acc[1 * 8 + c]),
                                relu_f(acc[2 * 8 + c]), relu_f(acc[3 * 8 + c]));
        float4 v1 = make_float4(relu_f(acc[4 * 8 + c]), relu_f(acc[5 * 8 + c]),
                                relu_f(acc[6 * 8 + c]), relu_f(acc[7 * 8 + c]));
        *(float4*)&sZ[col * ZS + nA] = v0;
        *(float4*)&sZ[col * ZS + 64 + nA] = v1;
    }

    float acc2[64];
    {
        const float4 b0 = *(const float4*)&bb[c0];
        const float4 b1 = *(const float4*)&bb[64 + c0];
#pragma unroll
        for (int j = 0; j < 8; ++j) {
            acc2[j * 8 + 0] = b0.x; acc2[j * 8 + 1] = b0.y; acc2[j * 8 + 2] = b0.z; acc2[j * 8 + 3] = b0.w;
            acc2[j * 8 + 4] = b1.x; acc2[j * 8 + 5] = b1.y; acc2[j * 8 + 6] = b1.z; acc2[j * 8 + 7] = b1.w;
        }
    }

    // ---- matmul 2: out = relu(T @ Wb + bb) ----
#pragma unroll 1
    for (int hh = 0; hh < 2; ++hh) {
        __syncthreads();
        for (int i = t; i < 64 * H; i += 256) sW[i] = Wb[hh * 64 * H + i];
        __syncthreads();
#pragma unroll 2
        for (int k2 = 0; k2 < 64; ++k2) {
            int k = hh * 64 + k2;
            const float4 w0 = *(const float4*)&sW[k2 * H + c0];
            const float4 w1 = *(const float4*)&sW[k2 * H + 64 + c0];
            const float4 z0 = *(const float4*)&sZ[k * ZS + nA];
            const float4 z1 = *(const float4*)&sZ[k * ZS + 64 + nA];
            float zz[8] = {z0.x, z0.y, z0.z, z0.w, z1.x, z1.y, z1.z, z1.w};
            float ww[8] = {w0.x, w0.y, w0.z, w0.w, w1.x, w1.y, w1.z, w1.w};
#pragma unroll
            for (int j = 0; j < 8; ++j)
#pragma unroll
                for (int c = 0; c < 8; ++c)
                    acc2[j * 8 + c] = fmaf(zz[j], ww[c], acc2[j * 8 + c]);
        }
    }

#pragma unroll
    for (int j = 0; j < 8; ++j) {
        int nloc = (j < 4) ? (nA + j) : (64 + nA + (j - 4));
        int node = n0 + nloc;
        if (node < n) {
            float4 o0 = make_float4(relu_f(acc2[j * 8 + 0]), relu_f(acc2[j * 8 + 1]),
                                    relu_f(acc2[j * 8 + 2]), relu_f(acc2[j * 8 + 3]));
            float4 o1 = make_float4(relu_f(acc2[j * 8 + 4]), relu_f(acc2[j * 8 + 5]),
                                    relu_f(acc2[j * 8 + 6]), relu_f(acc2[j * 8 + 7]));
            *(float4*)&h[(size_t)node * H + c0] = o0;
            *(float4*)&h[(size_t)node * H + 64 + c0] = o1;
        }
    }
}

// ---------------- input projection + refine + node-label embedding ----------------
// h = (relu(x*W_in + b_in) @ W_ref + b_ref) + node_emb[id]   (no outer relu)

__global__ __launch_bounds__(256) void input_proj_kernel(
    const float* __restrict__ nf,
    const float* __restrict__ W_in, const float* __restrict__ b_in,
    const float* __restrict__ W_ref, const float* __restrict__ b_ref,
    const float* __restrict__ node_emb, int n, float* __restrict__ h) {
    __shared__ __align__(16) float sZ[H * ZS];
    __shared__ __align__(16) float sW[64 * H];
    __shared__ float sx[BN];
    __shared__ int sid[BN];
    const int t = threadIdx.x;
    const int n0 = blockIdx.x * BN;
    const int cg = t & 15, ng = t >> 4;
    const int c0 = 4 * cg, nA = 4 * ng;

    if (t < BN) {
        int nn = n0 + t;
        float xv = (nn < n) ? nf[nn] : 0.f;
        sx[t] = fminf(fmaxf(xv / TWO48F, 0.f), 1.f);
        sid[t] = (nn < n) ? (((int)xv) & (NNODE_LBL - 1)) : 0;
    }
    __syncthreads();
    for (int idx = t; idx < BN * H; idx += 256) {
        int nn = idx >> 7, k = idx & 127;
        sZ[k * ZS + nn] = fmaxf(fmaf(sx[nn], W_in[k], b_in[k]), 0.f);
    }

    float acc[64];
    {
        const float4 b0 = *(const float4*)&b_ref[c0];
        const float4 b1 = *(const float4*)&b_ref[64 + c0];
#pragma unroll
        for (int j = 0; j < 8; ++j) {
            acc[j * 8 + 0] = b0.x; acc[j * 8 + 1] = b0.y; acc[j * 8 + 2] = b0.z; acc[j * 8 + 3] = b0.w;
            acc[j * 8 + 4] = b1.x; acc[j * 8 + 5] = b1.y; acc[j * 8 + 6] = b1.z; acc[j * 8 + 7] = b1.w;
        }
    }

#pragma unroll 1
    for (int hh = 0; hh < 2; ++hh) {
        __syncthreads();
        for (int i = t; i < 64 * H; i += 256) sW[i] = W_ref[hh * 64 * H + i];
        __syncthreads();
#pragma unroll 2
        for (int k2 = 0; k2 < 64; ++k2) {
            int k = hh * 64 + k2;
            const float4 w0 = *(const float4*)&sW[k2 * H + c0];
            const float4 w1 = *(const float4*)&sW[k2 * H + 64 + c0];
            const float4 z0 = *(const float4*)&sZ[k * ZS + nA];
            const float4 z1 = *(const float4*)&sZ[k * ZS + 64 + nA];
            float zz[8] = {z0.x, z0.y, z0.z, z0.w, z1.x, z1.y, z1.z, z1.w};
            float ww[8] = {w0.x, w0.y, w0.z, w0.w, w1.x, w1.y, w1.z, w1.w};
#pragma unroll
            for (int j = 0; j < 8; ++j)
#pragma unroll
                for (int c = 0; c < 8; ++c)
                    acc[j * 8 + c] = fmaf(zz[j], ww[c], acc[j * 8 + c]);
        }
    }

#pragma unroll
    for (int j = 0; j < 8; ++j) {
        int nloc = (j < 4) ? (nA + j) : (64 + nA + (j - 4));
        int node = n0 + nloc;
        if (node < n) {
            int id = sid[nloc];
            const float4 e0 = *(const float4*)&node_emb[(size_t)id * H + c0];
            const float4 e1 = *(const float4*)&node_emb[(size_t)id * H + 64 + c0];
            float4 o0 = make_float4(acc[j * 8 + 0] + e0.x, acc[j * 8 + 1] + e0.y,
                                    acc[j * 8 + 2] + e0.z, acc[j * 8 + 3] + e0.w);
            float4 o1 = make_float4(acc[j * 8 + 4] + e1.x, acc[j * 8 + 5] + e1.y,
                                    acc[j * 8 + 6] + e1.z, acc[j * 8 + 7] + e1.w);
            *(float4*)&h[(size_t)node * H + c0] = o0;
            *(float4*)&h[(size_t)node * H + 64 + c0] = o1;
        }
    }
}

// ---------------- host launcher ----------------

extern "C" void kernel_launch(void* const* d_in, const int* in_sizes, int n_in,
                              void* d_out, int out_size, void* d_ws, size_t ws_size,
                              hipStream_t stream) {
    const float* nf       = (const float*)d_in[0];
    const int*   eidx     = (const int*)d_in[1];
    const int*   eattr    = (const int*)d_in[2];
    const float* W_in     = (const float*)d_in[3];
    const float* b_in     = (const float*)d_in[4];
    const float* W_ref    = (const float*)d_in[5];
    const float* b_ref    = (const float*)d_in[6];
    const float* node_emb = (const float*)d_in[7];
    const float* edge_emb = (const float*)d_in[8];
    const float* Pe1      = (const float*)d_in[9];
    const float* be1      = (const float*)d_in[10];
    const float* Pe2      = (const float*)d_in[11];
    const float* be2      = (const float*)d_in[12];
    const float* W_lin    = (const float*)d_in[13];
    const float* b_lin    = (const float*)d_in[14];
    const float* W_a      = (const float*)d_in[15];
    const float* b_a      = (const float*)d_in[16];
    const float* W_b      = (const float*)d_in[17];
    const float* b_b      = (const float*)d_in[18];

    const int N = in_sizes[0];        // node count (node_features is [N,1])
    const int E = in_sizes[2];        // edge count
    const int* src = eidx;
    const int* dst = eidx + E;

    char* ws = (char*)d_ws;
    size_t off = 0;
    auto carve = [&](size_t bytes) -> void* {
        void* p = (void*)(ws + off);
        off = (off + bytes + 511) & ~(size_t)511;
        return p;
    };
    float* z      = (float*)carve((size_t)N * H * sizeof(float));
    int*   sorted = (int*)carve((size_t)E * sizeof(int));
    int*   rowptr = (int*)carve((size_t)(N + 1) * sizeof(int));
    int*   deg    = (int*)carve((size_t)N * sizeof(int));
    int*   cursor = (int*)carve((size_t)N * sizeof(int));
    const int NB  = (N + 1023) / 1024;
    int*   bsum   = (int*)carve((size_t)NB * sizeof(int));
    float* el_tab = (float*)carve((size_t)LAYERS * NLBL * H * sizeof(float));
    float* e_proj = (float*)carve((size_t)NLBL * ED * sizeof(float));
    float* h = (float*)d_out;

    // CSR build
    hipMemsetAsync(deg, 0, (size_t)N * sizeof(int), stream);
    hist_kernel<<<(E + 255) / 256, 256, 0, stream>>>(dst, E, deg);
    scan_block_sums<<<NB, 1024, 0, stream>>>(deg, N, bsum);
    scan_bsum<<<1, 64, 0, stream>>>(bsum, NB, rowptr + N);
    scan_final<<<NB, 1024, 0, stream>>>(deg, N, bsum, rowptr);
    hipMemsetAsync(cursor, 0, (size_t)N * sizeof(int), stream);
    scatter_kernel<<<(E + 255) / 256, 256, 0, stream>>>(src, dst, eattr, E, rowptr, cursor, sorted);

    // edge feature tables (256 labels only)
    edge_proj_kernel<<<NLBL, ED, 0, stream>>>(edge_emb, Pe1, be1, Pe2, be2, e_proj);
    el_tab_kernel<<<dim3(NLBL, LAYERS), H, 0, stream>>>(e_proj, W_lin, b_lin, el_tab);

    // node path
    const int gridMM = (N + BN - 1) / BN;
    input_proj_kernel<<<gridMM, 256, 0, stream>>>(nf, W_in, b_in, W_ref, b_ref, node_emb, N, h);

    for (int l = 0; l < LAYERS; ++l) {
        gather_kernel<<<(N + 3) / 4, 256, 0, stream>>>(
            h, rowptr, sorted, el_tab + (size_t)l * NLBL * H, N, z);
        mlp_kernel<<<gridMM, 256, 0, stream>>>(
            z, W_a + (size_t)l * H * H, b_a + (size_t)l * H,
            W_b + (size_t)l * H * H, b_b + (size_t)l * H, N, h);
    }
}

// Round 2
// 1241.960 us; speedup vs baseline: 1.1255x; 1.1255x over previous
//
#include <hip/hip_runtime.h>

#define H 128
#define ED 32
#define NLBL 256
#define NNODE_LBL 4096
#define LAYERS 3

typedef short bf16x8 __attribute__((ext_vector_type(8)));
typedef float f32x4 __attribute__((ext_vector_type(4)));

#define TWO48F 281474976710655.0f

static __device__ __forceinline__ float relu_f(float x) { return fmaxf(x, 0.f); }

static __device__ __forceinline__ unsigned short f2bf(float x) {
    unsigned u = __float_as_uint(x);
    return (unsigned short)((u + 0x7fffu + ((u >> 16) & 1u)) >> 16);
}

static __device__ __forceinline__ void split8(const float f[8], bf16x8& h, bf16x8& l) {
#pragma unroll
    for (int j = 0; j < 8; ++j) {
        unsigned short hh = f2bf(f[j]);
        float rem = f[j] - __uint_as_float(((unsigned)hh) << 16);
        h[j] = (short)hh;
        l[j] = (short)f2bf(rem);
    }
}

// ---------------- weight pre-split: fp32 [k][c] -> bf16 hi/lo transposed [c][k] ----------------
// matrices: 0 = W_ref, 1..3 = W_a[l], 4..6 = W_b[l]

__global__ void split_weights_kernel(const float* __restrict__ W_ref,
                                     const float* __restrict__ W_a,
                                     const float* __restrict__ W_b,
                                     unsigned short* __restrict__ hi,
                                     unsigned short* __restrict__ lo) {
    int mat = blockIdx.y;
    const float* src = (mat == 0) ? W_ref
                     : (mat <= 3) ? W_a + (size_t)(mat - 1) * H * H
                                  : W_b + (size_t)(mat - 4) * H * H;
    int idx = blockIdx.x * 256 + threadIdx.x;      // [0, 16384)
    int k = idx >> 7, c = idx & 127;
    float v = src[idx];                             // src[k*H + c]
    unsigned short hh = f2bf(v);
    float rem = v - __uint_as_float(((unsigned)hh) << 16);
    size_t o = (size_t)mat * H * H + (size_t)c * H + k;
    hi[o] = hh;
    lo[o] = f2bf(rem);
}

// ---------------- edge feature path (256 distinct labels only) ----------------

__global__ void edge_proj_kernel(const float* __restrict__ emb,
                                 const float* __restrict__ Pe1, const float* __restrict__ be1,
                                 const float* __restrict__ Pe2, const float* __restrict__ be2,
                                 float* __restrict__ e_proj) {
    int a = blockIdx.x, d = threadIdx.x;
    __shared__ float t[ED];
    float acc = be1[d];
    for (int k = 0; k < ED; ++k) acc = fmaf(emb[a * ED + k], Pe1[k * ED + d], acc);
    t[d] = fmaxf(acc, 0.f);
    __syncthreads();
    float acc2 = be2[d];
    for (int k = 0; k < ED; ++k) acc2 = fmaf(t[k], Pe2[k * ED + d], acc2);
    e_proj[a * ED + d] = acc2;
}

__global__ void el_tab_kernel(const float* __restrict__ e_proj,
                              const float* __restrict__ W_lin, const float* __restrict__ b_lin,
                              float* __restrict__ el_tab) {
    int a = blockIdx.x, l = blockIdx.y, k = threadIdx.x;
    float acc = b_lin[l * H + k];
    for (int d = 0; d < ED; ++d)
        acc = fmaf(e_proj[a * ED + d], W_lin[(l * ED + d) * H + k], acc);
    el_tab[((size_t)l * NLBL + a) * H + k] = acc;
}

// ---------------- CSR build (histogram -> scan -> scatter) ----------------

__global__ void hist_kernel(const int* __restrict__ dst, int E, int* __restrict__ deg) {
    int e = blockIdx.x * blockDim.x + threadIdx.x;
    if (e < E) atomicAdd(&deg[dst[e]], 1);
}

__global__ void scan_block_sums(const int* __restrict__ deg, int n, int* __restrict__ bsum) {
    __shared__ int s[1024];
    int i = blockIdx.x * 1024 + threadIdx.x;
    s[threadIdx.x] = (i < n) ? deg[i] : 0;
    __syncthreads();
    for (int off = 512; off > 0; off >>= 1) {
        if (threadIdx.x < off) s[threadIdx.x] += s[threadIdx.x + off];
        __syncthreads();
    }
    if (threadIdx.x == 0) bsum[blockIdx.x] = s[0];
}

__global__ void scan_bsum(int* __restrict__ bsum, int nb, int* __restrict__ total_out) {
    if (threadIdx.x == 0) {
        int run = 0;
        for (int b = 0; b < nb; ++b) { int v = bsum[b]; bsum[b] = run; run += v; }
        *total_out = run;
    }
}

__global__ void scan_final(const int* __restrict__ deg, int n,
                           const int* __restrict__ bsum, int* __restrict__ rowptr) {
    __shared__ int s[1024];
    int i = blockIdx.x * 1024 + threadIdx.x;
    int v = (i < n) ? deg[i] : 0;
    s[threadIdx.x] = v;
    __syncthreads();
    for (int off = 1; off < 1024; off <<= 1) {
        int add = (threadIdx.x >= off) ? s[threadIdx.x - off] : 0;
        __syncthreads();
        s[threadIdx.x] += add;
        __syncthreads();
    }
    if (i < n) rowptr[i] = bsum[blockIdx.x] + s[threadIdx.x] - v;
}

__global__ void scatter_kernel(const int* __restrict__ src, const int* __restrict__ dst,
                               const int* __restrict__ attr, int E,
                               const int* __restrict__ rowptr, int* __restrict__ cursor,
                               int* __restrict__ sorted) {
    int e = blockIdx.x * blockDim.x + threadIdx.x;
    if (e < E) {
        int d = dst[e];
        int pos = rowptr[d] + atomicAdd(&cursor[d], 1);
        sorted[pos] = src[e] | (attr[e] << 17);
    }
}

// ---------------- per-node aggregation: z = h + sum relu(h[src] + el[attr]) ----------------

__global__ __launch_bounds__(256) void gather_kernel(
    const float* __restrict__ h, const int* __restrict__ rowptr,
    const int* __restrict__ sorted, const float* __restrict__ el_tab_l,
    int n, float* __restrict__ z) {
    int wave = threadIdx.x >> 6;
    int lane = threadIdx.x & 63;
    int i = blockIdx.x * 4 + wave;
    if (i >= n) return;
    int beg = rowptr[i], end = rowptr[i + 1];
    const float2* h2 = (const float2*)h;
    const float2* e2 = (const float2*)el_tab_l;
    float accx = 0.f, accy = 0.f;
    for (int e = beg; e < end; ++e) {
        int p = sorted[e];
        int s = p & 131071;
        int a = p >> 17;
        float2 hv = h2[(size_t)s * 64 + lane];
        float2 ev = e2[(size_t)a * 64 + lane];
        accx += fmaxf(hv.x + ev.x, 0.f);
        accy += fmaxf(hv.y + ev.y, 0.f);
    }
    float2 hi = h2[(size_t)i * 64 + lane];
    float2 o; o.x = hi.x + accx; o.y = hi.y + accy;
    ((float2*)z)[(size_t)i * 64 + lane] = o;
}

// ---------------- MFMA fused MLP: h = relu(relu(z@Wa+ba)@Wb+bb), bf16 hi/lo split ----------------
// 2 waves/block, 32 nodes/wave. T staged per-wave in LDS bf16 hi/lo with XOR swizzle
// k' = k ^ 8*(node&7). Weights read as B-frags straight from pre-split global [col][k].

__global__ __launch_bounds__(128) void mlp_mfma_kernel(
    const float* __restrict__ z,
    const unsigned short* __restrict__ WAhi, const unsigned short* __restrict__ WAlo,
    const float* __restrict__ ba,
    const unsigned short* __restrict__ WBhi, const unsigned short* __restrict__ WBlo,
    const float* __restrict__ bb,
    int n, float* __restrict__ h) {
    __shared__ short sT[2][2][32 * H];
    const int t = threadIdx.x;
    const int w = t >> 6, lane = t & 63;
    const int m = lane & 15, g = lane >> 4;
    const int nb = blockIdx.x * 64 + w * 32;

    // ---- load z fragments (hi/lo split); A-frag: lane holds row m, k = 32ks+8g..+8 ----
    bf16x8 zh[2][4], zl[2][4];
#pragma unroll
    for (int rt = 0; rt < 2; ++rt) {
        int row = nb + 16 * rt + m; if (row >= n) row = n - 1;
        const float* zr = z + (size_t)row * H;
#pragma unroll
        for (int ks = 0; ks < 4; ++ks) {
            float f[8];
            float4 a = *(const float4*)(zr + 32 * ks + 8 * g);
            float4 b = *(const float4*)(zr + 32 * ks + 8 * g + 4);
            f[0] = a.x; f[1] = a.y; f[2] = a.z; f[3] = a.w;
            f[4] = b.x; f[5] = b.y; f[6] = b.z; f[7] = b.w;
            split8(f, zh[rt][ks], zl[rt][ks]);
        }
    }

    // ---- matmul1: T = relu(z@Wa + ba) -> LDS ----
#pragma unroll 1
    for (int ct = 0; ct < 8; ++ct) {
        float bias = ba[16 * ct + m];
        f32x4 c1[2];
        c1[0] = (f32x4){bias, bias, bias, bias};
        c1[1] = c1[0];
#pragma unroll
        for (int ks = 0; ks < 4; ++ks) {
            const size_t wo = (size_t)(16 * ct + m) * H + 32 * ks + 8 * g;
            bf16x8 bh = *(const bf16x8*)(WAhi + wo);
            bf16x8 bl = *(const bf16x8*)(WAlo + wo);
#pragma unroll
            for (int rt = 0; rt < 2; ++rt) {
                c1[rt] = __builtin_amdgcn_mfma_f32_16x16x32_bf16(zh[rt][ks], bh, c1[rt], 0, 0, 0);
                c1[rt] = __builtin_amdgcn_mfma_f32_16x16x32_bf16(zl[rt][ks], bh, c1[rt], 0, 0, 0);
                c1[rt] = __builtin_amdgcn_mfma_f32_16x16x32_bf16(zh[rt][ks], bl, c1[rt], 0, 0, 0);
            }
        }
        // C-frag: row = 4g+r (node), col = 16ct+m; write relu(T) hi/lo swizzled
#pragma unroll
        for (int rt = 0; rt < 2; ++rt) {
#pragma unroll
            for (int r = 0; r < 4; ++r) {
                float v = fmaxf(c1[rt][r], 0.f);
                unsigned short hh = f2bf(v);
                float rem = v - __uint_as_float(((unsigned)hh) << 16);
                unsigned short ll = f2bf(rem);
                int nl = 16 * rt + 4 * g + r;
                int kk = (16 * ct + m) ^ (8 * (nl & 7));
                sT[w][0][nl * H + kk] = (short)hh;
                sT[w][1][nl * H + kk] = (short)ll;
            }
        }
    }

    __syncthreads();

    // ---- matmul2: out = relu(T@Wb + bb) ----
    f32x4 c2[2][8];
#pragma unroll
    for (int ct = 0; ct < 8; ++ct) {
        float bias = bb[16 * ct + m];
        c2[0][ct] = (f32x4){bias, bias, bias, bias};
        c2[1][ct] = c2[0][ct];
    }
#pragma unroll 1
    for (int ks = 0; ks < 4; ++ks) {
        bf16x8 th[2], tl[2];
#pragma unroll
        for (int rt = 0; rt < 2; ++rt) {
            int nl = 16 * rt + m;
            int kk = (32 * ks + 8 * g) ^ (8 * (nl & 7));
            th[rt] = *(const bf16x8*)&sT[w][0][nl * H + kk];
            tl[rt] = *(const bf16x8*)&sT[w][1][nl * H + kk];
        }
#pragma unroll
        for (int ct = 0; ct < 8; ++ct) {
            const size_t wo = (size_t)(16 * ct + m) * H + 32 * ks + 8 * g;
            bf16x8 bh = *(const bf16x8*)(WBhi + wo);
            bf16x8 bl = *(const bf16x8*)(WBlo + wo);
#pragma unroll
            for (int rt = 0; rt < 2; ++rt) {
                c2[rt][ct] = __builtin_amdgcn_mfma_f32_16x16x32_bf16(th[rt], bh, c2[rt][ct], 0, 0, 0);
                c2[rt][ct] = __builtin_amdgcn_mfma_f32_16x16x32_bf16(tl[rt], bh, c2[rt][ct], 0, 0, 0);
                c2[rt][ct] = __builtin_amdgcn_mfma_f32_16x16x32_bf16(th[rt], bl, c2[rt][ct], 0, 0, 0);
            }
        }
    }

    // ---- epilogue ----
#pragma unroll
    for (int rt = 0; rt < 2; ++rt)
#pragma unroll
        for (int r = 0; r < 4; ++r) {
            int node = nb + 16 * rt + 4 * g + r;
            if (node < n) {
                float* hp = h + (size_t)node * H + m;
#pragma unroll
                for (int ct = 0; ct < 8; ++ct)
                    hp[16 * ct] = fmaxf(c2[rt][ct][r], 0.f);
            }
        }
}

// ---------------- input proj (rank-1 first layer) + refine matmul + node emb, MFMA ----------------

__global__ __launch_bounds__(128) void input_proj_mfma_kernel(
    const float* __restrict__ nf,
    const float* __restrict__ W_in, const float* __restrict__ b_in,
    const unsigned short* __restrict__ WRhi, const unsigned short* __restrict__ WRlo,
    const float* __restrict__ b_ref,
    const float* __restrict__ node_emb,
    int n, float* __restrict__ h) {
    __shared__ float sx[64];
    __shared__ int sid[64];
    const int t = threadIdx.x;
    const int w = t >> 6, lane = t & 63;
    const int m = lane & 15, g = lane >> 4;
    const int nb0 = blockIdx.x * 64;
    if (t < 64) {
        int node = nb0 + t;
        float xv = (node < n) ? nf[node] : 0.f;
        sx[t] = fminf(fmaxf(xv / TWO48F, 0.f), 1.f);
        sid[t] = ((int)xv) & (NNODE_LBL - 1);
    }
    __syncthreads();
    const int nb = nb0 + w * 32;

    // T0[node][k] = relu(x_node * W_in[k] + b_in[k]) computed directly into A-frags
    bf16x8 th[2][4], tl[2][4];
#pragma unroll
    for (int rt = 0; rt < 2; ++rt) {
        float xv = sx[w * 32 + 16 * rt + m];
#pragma unroll
        for (int ks = 0; ks < 4; ++ks) {
            float4 w0 = *(const float4*)(W_in + 32 * ks + 8 * g);
            float4 w1 = *(const float4*)(W_in + 32 * ks + 8 * g + 4);
            float4 b0 = *(const float4*)(b_in + 32 * ks + 8 * g);
            float4 b1 = *(const float4*)(b_in + 32 * ks + 8 * g + 4);
            float f[8];
            f[0] = relu_f(fmaf(xv, w0.x, b0.x)); f[1] = relu_f(fmaf(xv, w0.y, b0.y));
            f[2] = relu_f(fmaf(xv, w0.z, b0.z)); f[3] = relu_f(fmaf(xv, w0.w, b0.w));
            f[4] = relu_f(fmaf(xv, w1.x, b1.x)); f[5] = relu_f(fmaf(xv, w1.y, b1.y));
            f[6] = relu_f(fmaf(xv, w1.z, b1.z)); f[7] = relu_f(fmaf(xv, w1.w, b1.w));
            split8(f, th[rt][ks], tl[rt][ks]);
        }
    }

    f32x4 c2[2][8];
#pragma unroll
    for (int ct = 0; ct < 8; ++ct) {
        float bias = b_ref[16 * ct + m];
        c2[0][ct] = (f32x4){bias, bias, bias, bias};
        c2[1][ct] = c2[0][ct];
    }
#pragma unroll 1
    for (int ks = 0; ks < 4; ++ks) {
#pragma unroll
        for (int ct = 0; ct < 8; ++ct) {
            const size_t wo = (size_t)(16 * ct + m) * H + 32 * ks + 8 * g;
            bf16x8 bh = *(const bf16x8*)(WRhi + wo);
            bf16x8 bl = *(const bf16x8*)(WRlo + wo);
#pragma unroll
            for (int rt = 0; rt < 2; ++rt) {
                c2[rt][ct] = __builtin_amdgcn_mfma_f32_16x16x32_bf16(th[rt][ks], bh, c2[rt][ct], 0, 0, 0);
                c2[rt][ct] = __builtin_amdgcn_mfma_f32_16x16x32_bf16(tl[rt][ks], bh, c2[rt][ct], 0, 0, 0);
                c2[rt][ct] = __builtin_amdgcn_mfma_f32_16x16x32_bf16(th[rt][ks], bl, c2[rt][ct], 0, 0, 0);
            }
        }
    }

    // epilogue: + node_emb[id], NO outer relu
#pragma unroll
    for (int rt = 0; rt < 2; ++rt)
#pragma unroll
        for (int r = 0; r < 4; ++r) {
            int node = nb + 16 * rt + 4 * g + r;
            if (node < n) {
                int id = sid[w * 32 + 16 * rt + 4 * g + r];
                const float* ep = node_emb + (size_t)id * H + m;
                float* hp = h + (size_t)node * H + m;
#pragma unroll
                for (int ct = 0; ct < 8; ++ct)
                    hp[16 * ct] = c2[rt][ct][r] + ep[16 * ct];
            }
        }
}

// ---------------- host launcher ----------------

extern "C" void kernel_launch(void* const* d_in, const int* in_sizes, int n_in,
                              void* d_out, int out_size, void* d_ws, size_t ws_size,
                              hipStream_t stream) {
    const float* nf       = (const float*)d_in[0];
    const int*   eidx     = (const int*)d_in[1];
    const int*   eattr    = (const int*)d_in[2];
    const float* W_in     = (const float*)d_in[3];
    const float* b_in     = (const float*)d_in[4];
    const float* W_ref    = (const float*)d_in[5];
    const float* b_ref    = (const float*)d_in[6];
    const float* node_emb = (const float*)d_in[7];
    const float* edge_emb = (const float*)d_in[8];
    const float* Pe1      = (const float*)d_in[9];
    const float* be1      = (const float*)d_in[10];
    const float* Pe2      = (const float*)d_in[11];
    const float* be2      = (const float*)d_in[12];
    const float* W_lin    = (const float*)d_in[13];
    const float* b_lin    = (const float*)d_in[14];
    const float* W_a      = (const float*)d_in[15];
    const float* b_a      = (const float*)d_in[16];
    const float* W_b      = (const float*)d_in[17];
    const float* b_b      = (const float*)d_in[18];

    const int N = in_sizes[0];
    const int E = in_sizes[2];
    const int* src = eidx;
    const int* dst = eidx + E;

    char* ws = (char*)d_ws;
    size_t off = 0;
    auto carve = [&](size_t bytes) -> void* {
        void* p = (void*)(ws + off);
        off = (off + bytes + 511) & ~(size_t)511;
        return p;
    };
    float* z      = (float*)carve((size_t)N * H * sizeof(float));
    int*   sorted = (int*)carve((size_t)E * sizeof(int));
    int*   rowptr = (int*)carve((size_t)(N + 1) * sizeof(int));
    int*   deg    = (int*)carve((size_t)N * sizeof(int));
    int*   cursor = (int*)carve((size_t)N * sizeof(int));
    const int NB  = (N + 1023) / 1024;
    int*   bsum   = (int*)carve((size_t)NB * sizeof(int));
    float* el_tab = (float*)carve((size_t)LAYERS * NLBL * H * sizeof(float));
    float* e_proj = (float*)carve((size_t)NLBL * ED * sizeof(float));
    unsigned short* wsp_hi = (unsigned short*)carve((size_t)7 * H * H * sizeof(unsigned short));
    unsigned short* wsp_lo = (unsigned short*)carve((size_t)7 * H * H * sizeof(unsigned short));
    float* h = (float*)d_out;

    // weight pre-split (bf16 hi/lo, transposed to [col][k])
    split_weights_kernel<<<dim3(64, 7), 256, 0, stream>>>(W_ref, W_a, W_b, wsp_hi, wsp_lo);

    // CSR build
    hipMemsetAsync(deg, 0, (size_t)N * sizeof(int), stream);
    hist_kernel<<<(E + 255) / 256, 256, 0, stream>>>(dst, E, deg);
    scan_block_sums<<<NB, 1024, 0, stream>>>(deg, N, bsum);
    scan_bsum<<<1, 64, 0, stream>>>(bsum, NB, rowptr + N);
    scan_final<<<NB, 1024, 0, stream>>>(deg, N, bsum, rowptr);
    hipMemsetAsync(cursor, 0, (size_t)N * sizeof(int), stream);
    scatter_kernel<<<(E + 255) / 256, 256, 0, stream>>>(src, dst, eattr, E, rowptr, cursor, sorted);

    // edge feature tables (256 labels only)
    edge_proj_kernel<<<NLBL, ED, 0, stream>>>(edge_emb, Pe1, be1, Pe2, be2, e_proj);
    el_tab_kernel<<<dim3(NLBL, LAYERS), H, 0, stream>>>(e_proj, W_lin, b_lin, el_tab);

    // node path
    const int gridMM = (N + 63) / 64;
    const unsigned short* WRhi = wsp_hi;
    const unsigned short* WRlo = wsp_lo;
    input_proj_mfma_kernel<<<gridMM, 128, 0, stream>>>(
        nf, W_in, b_in, WRhi, WRlo, b_ref, node_emb, N, h);

    for (int l = 0; l < LAYERS; ++l) {
        gather_kernel<<<(N + 3) / 4, 256, 0, stream>>>(
            h, rowptr, sorted, el_tab + (size_t)l * NLBL * H, N, z);
        mlp_mfma_kernel<<<gridMM, 128, 0, stream>>>(
            z,
            wsp_hi + (size_t)(1 + l) * H * H, wsp_lo + (size_t)(1 + l) * H * H,
            b_a + (size_t)l * H,
            wsp_hi + (size_t)(4 + l) * H * H, wsp_lo + (size_t)(4 + l) * H * H,
            b_b + (size_t)l * H,
            N, h);
    }
}

// Round 3
// 903.713 us; speedup vs baseline: 1.5467x; 1.3743x over previous
//
#include <hip/hip_runtime.h>

#define H 128
#define ED 32
#define NLBL 256
#define NNODE_LBL 4096
#define LAYERS 3

typedef short bf16x8 __attribute__((ext_vector_type(8)));
typedef float f32x4 __attribute__((ext_vector_type(4)));

#define TWO48F 281474976710655.0f

static __device__ __forceinline__ float relu_f(float x) { return fmaxf(x, 0.f); }

static __device__ __forceinline__ unsigned short f2bf(float x) {
    unsigned u = __float_as_uint(x);
    return (unsigned short)((u + 0x7fffu + ((u >> 16) & 1u)) >> 16);
}

// ---------------- weight prep: fp32 [k][c] -> bf16 transposed [c][k] ----------------
// matrices: 0 = W_ref, 1..3 = W_a[l], 4..6 = W_b[l]

__global__ void split_weights_kernel(const float* __restrict__ W_ref,
                                     const float* __restrict__ W_a,
                                     const float* __restrict__ W_b,
                                     unsigned short* __restrict__ out) {
    int mat = blockIdx.y;
    const float* src = (mat == 0) ? W_ref
                     : (mat <= 3) ? W_a + (size_t)(mat - 1) * H * H
                                  : W_b + (size_t)(mat - 4) * H * H;
    int idx = blockIdx.x * 256 + threadIdx.x;      // [0, 16384)
    int k = idx >> 7, c = idx & 127;
    out[(size_t)mat * H * H + (size_t)c * H + k] = f2bf(src[idx]);
}

// ---------------- edge feature path (256 distinct labels only) ----------------

__global__ void edge_proj_kernel(const float* __restrict__ emb,
                                 const float* __restrict__ Pe1, const float* __restrict__ be1,
                                 const float* __restrict__ Pe2, const float* __restrict__ be2,
                                 float* __restrict__ e_proj) {
    int a = blockIdx.x, d = threadIdx.x;
    __shared__ float t[ED];
    float acc = be1[d];
    for (int k = 0; k < ED; ++k) acc = fmaf(emb[a * ED + k], Pe1[k * ED + d], acc);
    t[d] = fmaxf(acc, 0.f);
    __syncthreads();
    float acc2 = be2[d];
    for (int k = 0; k < ED; ++k) acc2 = fmaf(t[k], Pe2[k * ED + d], acc2);
    e_proj[a * ED + d] = acc2;
}

__global__ void el_tab_kernel(const float* __restrict__ e_proj,
                              const float* __restrict__ W_lin, const float* __restrict__ b_lin,
                              float* __restrict__ el_tab) {
    int a = blockIdx.x, l = blockIdx.y, k = threadIdx.x;
    float acc = b_lin[l * H + k];
    for (int d = 0; d < ED; ++d)
        acc = fmaf(e_proj[a * ED + d], W_lin[(l * ED + d) * H + k], acc);
    el_tab[((size_t)l * NLBL + a) * H + k] = acc;
}

// ---------------- CSR build (histogram -> scan -> scatter) ----------------

__global__ void hist_kernel(const int* __restrict__ dst, int E, int* __restrict__ deg) {
    int e = blockIdx.x * blockDim.x + threadIdx.x;
    if (e < E) atomicAdd(&deg[dst[e]], 1);
}

__global__ void scan_block_sums(const int* __restrict__ deg, int n, int* __restrict__ bsum) {
    __shared__ int s[1024];
    int i = blockIdx.x * 1024 + threadIdx.x;
    s[threadIdx.x] = (i < n) ? deg[i] : 0;
    __syncthreads();
    for (int off = 512; off > 0; off >>= 1) {
        if (threadIdx.x < off) s[threadIdx.x] += s[threadIdx.x + off];
        __syncthreads();
    }
    if (threadIdx.x == 0) bsum[blockIdx.x] = s[0];
}

__global__ void scan_bsum(int* __restrict__ bsum, int nb, int* __restrict__ total_out) {
    if (threadIdx.x == 0) {
        int run = 0;
        for (int b = 0; b < nb; ++b) { int v = bsum[b]; bsum[b] = run; run += v; }
        *total_out = run;
    }
}

__global__ void scan_final(const int* __restrict__ deg, int n,
                           const int* __restrict__ bsum, int* __restrict__ rowptr) {
    __shared__ int s[1024];
    int i = blockIdx.x * 1024 + threadIdx.x;
    int v = (i < n) ? deg[i] : 0;
    s[threadIdx.x] = v;
    __syncthreads();
    for (int off = 1; off < 1024; off <<= 1) {
        int add = (threadIdx.x >= off) ? s[threadIdx.x - off] : 0;
        __syncthreads();
        s[threadIdx.x] += add;
        __syncthreads();
    }
    if (i < n) rowptr[i] = bsum[blockIdx.x] + s[threadIdx.x] - v;
}

__global__ void scatter_kernel(const int* __restrict__ src, const int* __restrict__ dst,
                               const int* __restrict__ attr, int E,
                               const int* __restrict__ rowptr, int* __restrict__ cursor,
                               int* __restrict__ sorted) {
    int e = blockIdx.x * blockDim.x + threadIdx.x;
    if (e < E) {
        int d = dst[e];
        int pos = rowptr[d] + atomicAdd(&cursor[d], 1);
        sorted[pos] = src[e] | (attr[e] << 17);
    }
}

// ---------------- per-node aggregation: z = h + sum relu(h[src] + el[attr]) ----------------

__global__ __launch_bounds__(256) void gather_kernel(
    const float* __restrict__ h, const int* __restrict__ rowptr,
    const int* __restrict__ sorted, const float* __restrict__ el_tab_l,
    int n, float* __restrict__ z) {
    int wave = threadIdx.x >> 6;
    int lane = threadIdx.x & 63;
    int i = blockIdx.x * 4 + wave;
    if (i >= n) return;
    int beg = rowptr[i], end = rowptr[i + 1];
    const float2* h2 = (const float2*)h;
    const float2* e2 = (const float2*)el_tab_l;
    float accx = 0.f, accy = 0.f;
    for (int e = beg; e < end; ++e) {
        int p = sorted[e];
        int s = p & 131071;
        int a = p >> 17;
        float2 hv = h2[(size_t)s * 64 + lane];
        float2 ev = e2[(size_t)a * 64 + lane];
        accx += fmaxf(hv.x + ev.x, 0.f);
        accy += fmaxf(hv.y + ev.y, 0.f);
    }
    float2 hi = h2[(size_t)i * 64 + lane];
    float2 o; o.x = hi.x + accx; o.y = hi.y + accy;
    ((float2*)z)[(size_t)i * 64 + lane] = o;
}

// ---------------- MFMA fused MLP: h = relu(relu(z@Wa+ba)@Wb+bb), plain bf16 ----------------
// 2 waves/block, 32 nodes/wave. T staged per-wave in LDS bf16 with XOR swizzle
// k' = k ^ 8*(node&7). Weights read as B-frags straight from pre-transposed global [col][k].
// NOTE: every frag-array index must be compile-time (rule #20: runtime idx -> scratch).

__global__ __launch_bounds__(128) void mlp_mfma_kernel(
    const float* __restrict__ z,
    const unsigned short* __restrict__ WA, const float* __restrict__ ba,
    const unsigned short* __restrict__ WB, const float* __restrict__ bb,
    int n, float* __restrict__ h) {
    __shared__ short sT[2][32 * H];
    const int t = threadIdx.x;
    const int w = t >> 6, lane = t & 63;
    const int m = lane & 15, g = lane >> 4;
    const int nb = blockIdx.x * 64 + w * 32;

    // ---- load z fragments; A-frag: lane holds row m, k = 32ks+8g..+8 ----
    bf16x8 za[2][4];
#pragma unroll
    for (int rt = 0; rt < 2; ++rt) {
        int row = nb + 16 * rt + m; if (row >= n) row = n - 1;
        const float* zr = z + (size_t)row * H;
#pragma unroll
        for (int ks = 0; ks < 4; ++ks) {
            float4 a = *(const float4*)(zr + 32 * ks + 8 * g);
            float4 b = *(const float4*)(zr + 32 * ks + 8 * g + 4);
            bf16x8 v;
            v[0] = (short)f2bf(a.x); v[1] = (short)f2bf(a.y);
            v[2] = (short)f2bf(a.z); v[3] = (short)f2bf(a.w);
            v[4] = (short)f2bf(b.x); v[5] = (short)f2bf(b.y);
            v[6] = (short)f2bf(b.z); v[7] = (short)f2bf(b.w);
            za[rt][ks] = v;
        }
    }

    // ---- matmul1: T = relu(z@Wa + ba) -> LDS ----
#pragma unroll 1
    for (int ct = 0; ct < 8; ++ct) {
        float bias = ba[16 * ct + m];
        f32x4 c1[2];
        c1[0] = (f32x4){bias, bias, bias, bias};
        c1[1] = c1[0];
#pragma unroll
        for (int ks = 0; ks < 4; ++ks) {
            bf16x8 bh = *(const bf16x8*)(WA + (size_t)(16 * ct + m) * H + 32 * ks + 8 * g);
            c1[0] = __builtin_amdgcn_mfma_f32_16x16x32_bf16(za[0][ks], bh, c1[0], 0, 0, 0);
            c1[1] = __builtin_amdgcn_mfma_f32_16x16x32_bf16(za[1][ks], bh, c1[1], 0, 0, 0);
        }
        // C-frag: row(node) = 4g+r, col = 16ct+m; write relu(T) swizzled
#pragma unroll
        for (int rt = 0; rt < 2; ++rt) {
#pragma unroll
            for (int r = 0; r < 4; ++r) {
                float v = fmaxf(c1[rt][r], 0.f);
                int nl = 16 * rt + 4 * g + r;
                int kk = (16 * ct + m) ^ (8 * (nl & 7));
                sT[w][nl * H + kk] = (short)f2bf(v);
            }
        }
    }

    __syncthreads();

    // ---- matmul2: out = relu(T@Wb + bb) ----
    f32x4 c2[2][8];
#pragma unroll
    for (int ct = 0; ct < 8; ++ct) {
        float bias = bb[16 * ct + m];
        c2[0][ct] = (f32x4){bias, bias, bias, bias};
        c2[1][ct] = c2[0][ct];
    }
#pragma unroll 1
    for (int ks = 0; ks < 4; ++ks) {
        bf16x8 ta[2];
#pragma unroll
        for (int rt = 0; rt < 2; ++rt) {
            int nl = 16 * rt + m;
            int kk = (32 * ks + 8 * g) ^ (8 * (nl & 7));
            ta[rt] = *(const bf16x8*)&sT[w][nl * H + kk];
        }
#pragma unroll
        for (int ct = 0; ct < 8; ++ct) {
            bf16x8 bh = *(const bf16x8*)(WB + (size_t)(16 * ct + m) * H + 32 * ks + 8 * g);
            c2[0][ct] = __builtin_amdgcn_mfma_f32_16x16x32_bf16(ta[0], bh, c2[0][ct], 0, 0, 0);
            c2[1][ct] = __builtin_amdgcn_mfma_f32_16x16x32_bf16(ta[1], bh, c2[1][ct], 0, 0, 0);
        }
    }

    // ---- epilogue: scalar stores (16-lane 64B segments per row) ----
#pragma unroll
    for (int rt = 0; rt < 2; ++rt)
#pragma unroll
        for (int r = 0; r < 4; ++r) {
            int node = nb + 16 * rt + 4 * g + r;
            if (node < n) {
                float* hp = h + (size_t)node * H + m;
#pragma unroll
                for (int ct = 0; ct < 8; ++ct)
                    hp[16 * ct] = fmaxf(c2[rt][ct][r], 0.f);
            }
        }
}

// ---------------- input proj (rank-1 first layer) + refine matmul + node emb, MFMA ----------------
// h = (relu(x*W_in + b_in) @ W_ref + b_ref) + node_emb[id]   (no outer relu)
// ALL loops fully unrolled: frag indices must be compile-time constants.

__global__ __launch_bounds__(128) void input_proj_mfma_kernel(
    const float* __restrict__ nf,
    const float* __restrict__ W_in, const float* __restrict__ b_in,
    const unsigned short* __restrict__ WR, const float* __restrict__ b_ref,
    const float* __restrict__ node_emb,
    int n, float* __restrict__ h) {
    __shared__ float sx[64];
    __shared__ int sid[64];
    const int t = threadIdx.x;
    const int w = t >> 6, lane = t & 63;
    const int m = lane & 15, g = lane >> 4;
    const int nb0 = blockIdx.x * 64;
    if (t < 64) {
        int node = nb0 + t;
        float xv = (node < n) ? nf[node] : 0.f;
        sx[t] = fminf(fmaxf(xv / TWO48F, 0.f), 1.f);
        sid[t] = ((int)xv) & (NNODE_LBL - 1);
    }
    __syncthreads();
    const int nb = nb0 + w * 32;

    // T0[node][k] = relu(x_node * W_in[k] + b_in[k]) computed directly into A-frags
    bf16x8 ta[2][4];
#pragma unroll
    for (int rt = 0; rt < 2; ++rt) {
        float xv = sx[w * 32 + 16 * rt + m];
#pragma unroll
        for (int ks = 0; ks < 4; ++ks) {
            float4 w0 = *(const float4*)(W_in + 32 * ks + 8 * g);
            float4 w1 = *(const float4*)(W_in + 32 * ks + 8 * g + 4);
            float4 b0 = *(const float4*)(b_in + 32 * ks + 8 * g);
            float4 b1 = *(const float4*)(b_in + 32 * ks + 8 * g + 4);
            bf16x8 v;
            v[0] = (short)f2bf(relu_f(fmaf(xv, w0.x, b0.x)));
            v[1] = (short)f2bf(relu_f(fmaf(xv, w0.y, b0.y)));
            v[2] = (short)f2bf(relu_f(fmaf(xv, w0.z, b0.z)));
            v[3] = (short)f2bf(relu_f(fmaf(xv, w0.w, b0.w)));
            v[4] = (short)f2bf(relu_f(fmaf(xv, w1.x, b1.x)));
            v[5] = (short)f2bf(relu_f(fmaf(xv, w1.y, b1.y)));
            v[6] = (short)f2bf(relu_f(fmaf(xv, w1.z, b1.z)));
            v[7] = (short)f2bf(relu_f(fmaf(xv, w1.w, b1.w)));
            ta[rt][ks] = v;
        }
    }

    f32x4 c2[2][8];
#pragma unroll
    for (int ct = 0; ct < 8; ++ct) {
        float bias = b_ref[16 * ct + m];
        c2[0][ct] = (f32x4){bias, bias, bias, bias};
        c2[1][ct] = c2[0][ct];
    }
#pragma unroll
    for (int ct = 0; ct < 8; ++ct) {
#pragma unroll
        for (int ks = 0; ks < 4; ++ks) {
            bf16x8 bh = *(const bf16x8*)(WR + (size_t)(16 * ct + m) * H + 32 * ks + 8 * g);
            c2[0][ct] = __builtin_amdgcn_mfma_f32_16x16x32_bf16(ta[0][ks], bh, c2[0][ct], 0, 0, 0);
            c2[1][ct] = __builtin_amdgcn_mfma_f32_16x16x32_bf16(ta[1][ks], bh, c2[1][ct], 0, 0, 0);
        }
    }

    // epilogue: + node_emb[id], NO outer relu
#pragma unroll
    for (int rt = 0; rt < 2; ++rt)
#pragma unroll
        for (int r = 0; r < 4; ++r) {
            int node = nb + 16 * rt + 4 * g + r;
            if (node < n) {
                int id = sid[w * 32 + 16 * rt + 4 * g + r];
                const float* ep = node_emb + (size_t)id * H + m;
                float* hp = h + (size_t)node * H + m;
#pragma unroll
                for (int ct = 0; ct < 8; ++ct)
                    hp[16 * ct] = c2[rt][ct][r] + ep[16 * ct];
            }
        }
}

// ---------------- host launcher ----------------

extern "C" void kernel_launch(void* const* d_in, const int* in_sizes, int n_in,
                              void* d_out, int out_size, void* d_ws, size_t ws_size,
                              hipStream_t stream) {
    const float* nf       = (const float*)d_in[0];
    const int*   eidx     = (const int*)d_in[1];
    const int*   eattr    = (const int*)d_in[2];
    const float* W_in     = (const float*)d_in[3];
    const float* b_in     = (const float*)d_in[4];
    const float* W_ref    = (const float*)d_in[5];
    const float* b_ref    = (const float*)d_in[6];
    const float* node_emb = (const float*)d_in[7];
    const float* edge_emb = (const float*)d_in[8];
    const float* Pe1      = (const float*)d_in[9];
    const float* be1      = (const float*)d_in[10];
    const float* Pe2      = (const float*)d_in[11];
    const float* be2      = (const float*)d_in[12];
    const float* W_lin    = (const float*)d_in[13];
    const float* b_lin    = (const float*)d_in[14];
    const float* W_a      = (const float*)d_in[15];
    const float* b_a      = (const float*)d_in[16];
    const float* W_b      = (const float*)d_in[17];
    const float* b_b      = (const float*)d_in[18];

    const int N = in_sizes[0];
    const int E = in_sizes[2];
    const int* src = eidx;
    const int* dst = eidx + E;

    char* ws = (char*)d_ws;
    size_t off = 0;
    auto carve = [&](size_t bytes) -> void* {
        void* p = (void*)(ws + off);
        off = (off + bytes + 511) & ~(size_t)511;
        return p;
    };
    float* z      = (float*)carve((size_t)N * H * sizeof(float));
    int*   sorted = (int*)carve((size_t)E * sizeof(int));
    int*   rowptr = (int*)carve((size_t)(N + 1) * sizeof(int));
    int*   deg    = (int*)carve((size_t)N * sizeof(int));
    int*   cursor = (int*)carve((size_t)N * sizeof(int));
    const int NB  = (N + 1023) / 1024;
    int*   bsum   = (int*)carve((size_t)NB * sizeof(int));
    float* el_tab = (float*)carve((size_t)LAYERS * NLBL * H * sizeof(float));
    float* e_proj = (float*)carve((size_t)NLBL * ED * sizeof(float));
    unsigned short* wsp = (unsigned short*)carve((size_t)7 * H * H * sizeof(unsigned short));
    float* h = (float*)d_out;

    // weight prep (bf16, transposed to [col][k])
    split_weights_kernel<<<dim3(64, 7), 256, 0, stream>>>(W_ref, W_a, W_b, wsp);

    // CSR build
    hipMemsetAsync(deg, 0, (size_t)N * sizeof(int), stream);
    hist_kernel<<<(E + 255) / 256, 256, 0, stream>>>(dst, E, deg);
    scan_block_sums<<<NB, 1024, 0, stream>>>(deg, N, bsum);
    scan_bsum<<<1, 64, 0, stream>>>(bsum, NB, rowptr + N);
    scan_final<<<NB, 1024, 0, stream>>>(deg, N, bsum, rowptr);
    hipMemsetAsync(cursor, 0, (size_t)N * sizeof(int), stream);
    scatter_kernel<<<(E + 255) / 256, 256, 0, stream>>>(src, dst, eattr, E, rowptr, cursor, sorted);

    // edge feature tables (256 labels only)
    edge_proj_kernel<<<NLBL, ED, 0, stream>>>(edge_emb, Pe1, be1, Pe2, be2, e_proj);
    el_tab_kernel<<<dim3(NLBL, LAYERS), H, 0, stream>>>(e_proj, W_lin, b_lin, el_tab);

    // node path
    const int gridMM = (N + 63) / 64;
    input_proj_mfma_kernel<<<gridMM, 128, 0, stream>>>(
        nf, W_in, b_in, wsp, b_ref, node_emb, N, h);

    for (int l = 0; l < LAYERS; ++l) {
        gather_kernel<<<(N + 3) / 4, 256, 0, stream>>>(
            h, rowptr, sorted, el_tab + (size_t)l * NLBL * H, N, z);
        mlp_mfma_kernel<<<gridMM, 128, 0, stream>>>(
            z,
            wsp + (size_t)(1 + l) * H * H, b_a + (size_t)l * H,
            wsp + (size_t)(4 + l) * H * H, b_b + (size_t)l * H,
            N, h);
    }
}

// Round 4
// 607.234 us; speedup vs baseline: 2.3019x; 1.4882x over previous
//
#include <hip/hip_runtime.h>

#define H 128
#define ED 32
#define NLBL 256
#define NNODE_LBL 4096
#define LAYERS 3

typedef short bf16x8 __attribute__((ext_vector_type(8)));
typedef float f32x4 __attribute__((ext_vector_type(4)));

#define TWO48F 281474976710655.0f

static __device__ __forceinline__ float relu_f(float x) { return fmaxf(x, 0.f); }

static __device__ __forceinline__ unsigned short f2bf(float x) {
    unsigned u = __float_as_uint(x);
    return (unsigned short)((u + 0x7fffu + ((u >> 16) & 1u)) >> 16);
}

static __device__ __forceinline__ float bf2f(short b) {
    return __uint_as_float(((unsigned)(unsigned short)b) << 16);
}

// ---------------- weight prep: fp32 [k][c] -> bf16 transposed [c][k] ----------------
// matrices: 0 = W_ref, 1..3 = W_a[l], 4..6 = W_b[l]

__global__ void split_weights_kernel(const float* __restrict__ W_ref,
                                     const float* __restrict__ W_a,
                                     const float* __restrict__ W_b,
                                     unsigned short* __restrict__ out) {
    int mat = blockIdx.y;
    const float* src = (mat == 0) ? W_ref
                     : (mat <= 3) ? W_a + (size_t)(mat - 1) * H * H
                                  : W_b + (size_t)(mat - 4) * H * H;
    int idx = blockIdx.x * 256 + threadIdx.x;      // [0, 16384)
    int k = idx >> 7, c = idx & 127;
    out[(size_t)mat * H * H + (size_t)c * H + k] = f2bf(src[idx]);
}

// ---------------- edge feature path (256 distinct labels only) ----------------

__global__ void edge_proj_kernel(const float* __restrict__ emb,
                                 const float* __restrict__ Pe1, const float* __restrict__ be1,
                                 const float* __restrict__ Pe2, const float* __restrict__ be2,
                                 float* __restrict__ e_proj) {
    int a = blockIdx.x, d = threadIdx.x;
    __shared__ float t[ED];
    float acc = be1[d];
    for (int k = 0; k < ED; ++k) acc = fmaf(emb[a * ED + k], Pe1[k * ED + d], acc);
    t[d] = fmaxf(acc, 0.f);
    __syncthreads();
    float acc2 = be2[d];
    for (int k = 0; k < ED; ++k) acc2 = fmaf(t[k], Pe2[k * ED + d], acc2);
    e_proj[a * ED + d] = acc2;
}

// el_tab in bf16 (gather consumes bf16)
__global__ void el_tab_kernel(const float* __restrict__ e_proj,
                              const float* __restrict__ W_lin, const float* __restrict__ b_lin,
                              unsigned short* __restrict__ el_tab) {
    int a = blockIdx.x, l = blockIdx.y, k = threadIdx.x;
    float acc = b_lin[l * H + k];
    for (int d = 0; d < ED; ++d)
        acc = fmaf(e_proj[a * ED + d], W_lin[(l * ED + d) * H + k], acc);
    el_tab[((size_t)l * NLBL + a) * H + k] = f2bf(acc);
}

// ---------------- CSR build (histogram -> scan -> scatter) ----------------

__global__ void hist_kernel(const int* __restrict__ dst, int E, int* __restrict__ deg) {
    int e = blockIdx.x * blockDim.x + threadIdx.x;
    if (e < E) atomicAdd(&deg[dst[e]], 1);
}

__global__ void scan_block_sums(const int* __restrict__ deg, int n, int* __restrict__ bsum) {
    __shared__ int s[1024];
    int i = blockIdx.x * 1024 + threadIdx.x;
    s[threadIdx.x] = (i < n) ? deg[i] : 0;
    __syncthreads();
    for (int off = 512; off > 0; off >>= 1) {
        if (threadIdx.x < off) s[threadIdx.x] += s[threadIdx.x + off];
        __syncthreads();
    }
    if (threadIdx.x == 0) bsum[blockIdx.x] = s[0];
}

__global__ void scan_bsum(int* __restrict__ bsum, int nb, int* __restrict__ total_out) {
    if (threadIdx.x == 0) {
        int run = 0;
        for (int b = 0; b < nb; ++b) { int v = bsum[b]; bsum[b] = run; run += v; }
        *total_out = run;
    }
}

__global__ void scan_final(const int* __restrict__ deg, int n,
                           const int* __restrict__ bsum, int* __restrict__ rowptr) {
    __shared__ int s[1024];
    int i = blockIdx.x * 1024 + threadIdx.x;
    int v = (i < n) ? deg[i] : 0;
    s[threadIdx.x] = v;
    __syncthreads();
    for (int off = 1; off < 1024; off <<= 1) {
        int add = (threadIdx.x >= off) ? s[threadIdx.x - off] : 0;
        __syncthreads();
        s[threadIdx.x] += add;
        __syncthreads();
    }
    if (i < n) rowptr[i] = bsum[blockIdx.x] + s[threadIdx.x] - v;
}

__global__ void scatter_kernel(const int* __restrict__ src, const int* __restrict__ dst,
                               const int* __restrict__ attr, int E,
                               const int* __restrict__ rowptr, int* __restrict__ cursor,
                               int* __restrict__ sorted) {
    int e = blockIdx.x * blockDim.x + threadIdx.x;
    if (e < E) {
        int d = dst[e];
        int pos = rowptr[d] + atomicAdd(&cursor[d], 1);
        sorted[pos] = src[e] | (attr[e] << 17);
    }
}

// ---------------- per-node aggregation: z = h + sum relu(h[src] + el[attr]) ----------------
// bf16 h/el/z. One wave per node; 4 edges in flight (4 groups x 16 lanes x 16B);
// fp32 accumulate; cross-group shfl_xor reduce; 16-lane bf16x8 z store.

__global__ __launch_bounds__(256) void gather_kernel(
    const unsigned short* __restrict__ hbf, const int* __restrict__ rowptr,
    const int* __restrict__ sorted, const unsigned short* __restrict__ el,
    int n, unsigned short* __restrict__ z) {
    int wave = threadIdx.x >> 6;
    int lane = threadIdx.x & 63;
    int i = blockIdx.x * 4 + wave;
    if (i >= n) return;
    int beg = rowptr[i], end = rowptr[i + 1];
    int gg = lane >> 4, m = lane & 15;
    float acc[8];
#pragma unroll
    for (int j = 0; j < 8; ++j) acc[j] = 0.f;
    for (int e = beg; e < end; e += 4) {
        int idx = e + gg;
        int p = (idx < end) ? sorted[idx] : -1;
        if (p >= 0) {
            int s = p & 131071;
            int a = p >> 17;
            bf16x8 hv = *(const bf16x8*)(hbf + (size_t)s * H + m * 8);
            bf16x8 ev = *(const bf16x8*)(el + (size_t)a * H + m * 8);
#pragma unroll
            for (int j = 0; j < 8; ++j)
                acc[j] += fmaxf(bf2f(hv[j]) + bf2f(ev[j]), 0.f);
        }
    }
#pragma unroll
    for (int j = 0; j < 8; ++j) {
        acc[j] += __shfl_xor(acc[j], 16, 64);
        acc[j] += __shfl_xor(acc[j], 32, 64);
    }
    if (gg == 0) {
        bf16x8 hv = *(const bf16x8*)(hbf + (size_t)i * H + m * 8);
        bf16x8 o;
#pragma unroll
        for (int j = 0; j < 8; ++j)
            o[j] = (short)f2bf(bf2f(hv[j]) + acc[j]);
        *(bf16x8*)(z + (size_t)i * H + m * 8) = o;
    }
}

// ---------------- MFMA fused MLP: h = relu(relu(z@Wa+ba)@Wb+bb), bf16 in, bf16/fp32 out ----
// 2 waves/block, 32 nodes/wave. T staged per-wave in LDS bf16 with XOR swizzle
// k' = k ^ 8*(node&7). Weights read as B-frags from pre-transposed global [col][k].
// All frag-array indices compile-time (rule #20).

__global__ __launch_bounds__(128) void mlp_mfma_kernel(
    const unsigned short* __restrict__ z,
    const unsigned short* __restrict__ WA, const float* __restrict__ ba,
    const unsigned short* __restrict__ WB, const float* __restrict__ bb,
    int n, unsigned short* __restrict__ hbf, float* __restrict__ hf32) {
    __shared__ short sT[2][32 * H];
    const int t = threadIdx.x;
    const int w = t >> 6, lane = t & 63;
    const int m = lane & 15, g = lane >> 4;
    const int nb = blockIdx.x * 64 + w * 32;

    // ---- load z fragments (direct bf16); A-frag: lane holds row m, k = 32ks+8g..+8 ----
    bf16x8 za[2][4];
#pragma unroll
    for (int rt = 0; rt < 2; ++rt) {
        int row = nb + 16 * rt + m; if (row >= n) row = n - 1;
        const unsigned short* zr = z + (size_t)row * H;
#pragma unroll
        for (int ks = 0; ks < 4; ++ks)
            za[rt][ks] = *(const bf16x8*)(zr + 32 * ks + 8 * g);
    }

    // ---- matmul1: T = relu(z@Wa + ba) -> LDS ----
#pragma unroll 1
    for (int ct = 0; ct < 8; ++ct) {
        float bias = ba[16 * ct + m];
        f32x4 c1[2];
        c1[0] = (f32x4){bias, bias, bias, bias};
        c1[1] = c1[0];
#pragma unroll
        for (int ks = 0; ks < 4; ++ks) {
            bf16x8 bh = *(const bf16x8*)(WA + (size_t)(16 * ct + m) * H + 32 * ks + 8 * g);
            c1[0] = __builtin_amdgcn_mfma_f32_16x16x32_bf16(za[0][ks], bh, c1[0], 0, 0, 0);
            c1[1] = __builtin_amdgcn_mfma_f32_16x16x32_bf16(za[1][ks], bh, c1[1], 0, 0, 0);
        }
        // C-frag: row(node) = 4g+r, col = 16ct+m; write relu(T) swizzled
#pragma unroll
        for (int rt = 0; rt < 2; ++rt) {
#pragma unroll
            for (int r = 0; r < 4; ++r) {
                float v = fmaxf(c1[rt][r], 0.f);
                int nl = 16 * rt + 4 * g + r;
                int kk = (16 * ct + m) ^ (8 * (nl & 7));
                sT[w][nl * H + kk] = (short)f2bf(v);
            }
        }
    }

    __syncthreads();

    // ---- matmul2: out = relu(T@Wb + bb) ----
    f32x4 c2[2][8];
#pragma unroll
    for (int ct = 0; ct < 8; ++ct) {
        float bias = bb[16 * ct + m];
        c2[0][ct] = (f32x4){bias, bias, bias, bias};
        c2[1][ct] = c2[0][ct];
    }
#pragma unroll 1
    for (int ks = 0; ks < 4; ++ks) {
        bf16x8 ta[2];
#pragma unroll
        for (int rt = 0; rt < 2; ++rt) {
            int nl = 16 * rt + m;
            int kk = (32 * ks + 8 * g) ^ (8 * (nl & 7));
            ta[rt] = *(const bf16x8*)&sT[w][nl * H + kk];
        }
#pragma unroll
        for (int ct = 0; ct < 8; ++ct) {
            bf16x8 bh = *(const bf16x8*)(WB + (size_t)(16 * ct + m) * H + 32 * ks + 8 * g);
            c2[0][ct] = __builtin_amdgcn_mfma_f32_16x16x32_bf16(ta[0], bh, c2[0][ct], 0, 0, 0);
            c2[1][ct] = __builtin_amdgcn_mfma_f32_16x16x32_bf16(ta[1], bh, c2[1][ct], 0, 0, 0);
        }
    }

    // ---- epilogue: intermediate layers -> bf16 h; final layer -> fp32 d_out ----
    if (hf32) {
#pragma unroll
        for (int rt = 0; rt < 2; ++rt)
#pragma unroll
            for (int r = 0; r < 4; ++r) {
                int node = nb + 16 * rt + 4 * g + r;
                if (node < n) {
                    float* hp = hf32 + (size_t)node * H + m;
#pragma unroll
                    for (int ct = 0; ct < 8; ++ct)
                        hp[16 * ct] = fmaxf(c2[rt][ct][r], 0.f);
                }
            }
    } else {
#pragma unroll
        for (int rt = 0; rt < 2; ++rt)
#pragma unroll
            for (int r = 0; r < 4; ++r) {
                int node = nb + 16 * rt + 4 * g + r;
                if (node < n) {
                    unsigned short* hp = hbf + (size_t)node * H + m;
#pragma unroll
                    for (int ct = 0; ct < 8; ++ct)
                        hp[16 * ct] = f2bf(fmaxf(c2[rt][ct][r], 0.f));
                }
            }
    }
}

// ---------------- input proj (rank-1 first layer) + refine matmul + node emb, MFMA ----------------
// h = (relu(x*W_in + b_in) @ W_ref + b_ref) + node_emb[id]   (no outer relu), bf16 out

__global__ __launch_bounds__(128) void input_proj_mfma_kernel(
    const float* __restrict__ nf,
    const float* __restrict__ W_in, const float* __restrict__ b_in,
    const unsigned short* __restrict__ WR, const float* __restrict__ b_ref,
    const float* __restrict__ node_emb,
    int n, unsigned short* __restrict__ hbf) {
    __shared__ float sx[64];
    __shared__ int sid[64];
    const int t = threadIdx.x;
    const int w = t >> 6, lane = t & 63;
    const int m = lane & 15, g = lane >> 4;
    const int nb0 = blockIdx.x * 64;
    if (t < 64) {
        int node = nb0 + t;
        float xv = (node < n) ? nf[node] : 0.f;
        sx[t] = fminf(fmaxf(xv / TWO48F, 0.f), 1.f);
        sid[t] = ((int)xv) & (NNODE_LBL - 1);
    }
    __syncthreads();
    const int nb = nb0 + w * 32;

    // T0[node][k] = relu(x_node * W_in[k] + b_in[k]) computed directly into A-frags
    bf16x8 ta[2][4];
#pragma unroll
    for (int rt = 0; rt < 2; ++rt) {
        float xv = sx[w * 32 + 16 * rt + m];
#pragma unroll
        for (int ks = 0; ks < 4; ++ks) {
            float4 w0 = *(const float4*)(W_in + 32 * ks + 8 * g);
            float4 w1 = *(const float4*)(W_in + 32 * ks + 8 * g + 4);
            float4 b0 = *(const float4*)(b_in + 32 * ks + 8 * g);
            float4 b1 = *(const float4*)(b_in + 32 * ks + 8 * g + 4);
            bf16x8 v;
            v[0] = (short)f2bf(relu_f(fmaf(xv, w0.x, b0.x)));
            v[1] = (short)f2bf(relu_f(fmaf(xv, w0.y, b0.y)));
            v[2] = (short)f2bf(relu_f(fmaf(xv, w0.z, b0.z)));
            v[3] = (short)f2bf(relu_f(fmaf(xv, w0.w, b0.w)));
            v[4] = (short)f2bf(relu_f(fmaf(xv, w1.x, b1.x)));
            v[5] = (short)f2bf(relu_f(fmaf(xv, w1.y, b1.y)));
            v[6] = (short)f2bf(relu_f(fmaf(xv, w1.z, b1.z)));
            v[7] = (short)f2bf(relu_f(fmaf(xv, w1.w, b1.w)));
            ta[rt][ks] = v;
        }
    }

    f32x4 c2[2][8];
#pragma unroll
    for (int ct = 0; ct < 8; ++ct) {
        float bias = b_ref[16 * ct + m];
        c2[0][ct] = (f32x4){bias, bias, bias, bias};
        c2[1][ct] = c2[0][ct];
    }
#pragma unroll
    for (int ct = 0; ct < 8; ++ct) {
#pragma unroll
        for (int ks = 0; ks < 4; ++ks) {
            bf16x8 bh = *(const bf16x8*)(WR + (size_t)(16 * ct + m) * H + 32 * ks + 8 * g);
            c2[0][ct] = __builtin_amdgcn_mfma_f32_16x16x32_bf16(ta[0][ks], bh, c2[0][ct], 0, 0, 0);
            c2[1][ct] = __builtin_amdgcn_mfma_f32_16x16x32_bf16(ta[1][ks], bh, c2[1][ct], 0, 0, 0);
        }
    }

    // epilogue: + node_emb[id], NO outer relu, bf16 store
#pragma unroll
    for (int rt = 0; rt < 2; ++rt)
#pragma unroll
        for (int r = 0; r < 4; ++r) {
            int node = nb + 16 * rt + 4 * g + r;
            if (node < n) {
                int id = sid[w * 32 + 16 * rt + 4 * g + r];
                const float* ep = node_emb + (size_t)id * H + m;
                unsigned short* hp = hbf + (size_t)node * H + m;
#pragma unroll
                for (int ct = 0; ct < 8; ++ct)
                    hp[16 * ct] = f2bf(c2[rt][ct][r] + ep[16 * ct]);
            }
        }
}

// ---------------- host launcher ----------------

extern "C" void kernel_launch(void* const* d_in, const int* in_sizes, int n_in,
                              void* d_out, int out_size, void* d_ws, size_t ws_size,
                              hipStream_t stream) {
    const float* nf       = (const float*)d_in[0];
    const int*   eidx     = (const int*)d_in[1];
    const int*   eattr    = (const int*)d_in[2];
    const float* W_in     = (const float*)d_in[3];
    const float* b_in     = (const float*)d_in[4];
    const float* W_ref    = (const float*)d_in[5];
    const float* b_ref    = (const float*)d_in[6];
    const float* node_emb = (const float*)d_in[7];
    const float* edge_emb = (const float*)d_in[8];
    const float* Pe1      = (const float*)d_in[9];
    const float* be1      = (const float*)d_in[10];
    const float* Pe2      = (const float*)d_in[11];
    const float* be2      = (const float*)d_in[12];
    const float* W_lin    = (const float*)d_in[13];
    const float* b_lin    = (const float*)d_in[14];
    const float* W_a      = (const float*)d_in[15];
    const float* b_a      = (const float*)d_in[16];
    const float* W_b      = (const float*)d_in[17];
    const float* b_b      = (const float*)d_in[18];

    const int N = in_sizes[0];
    const int E = in_sizes[2];
    const int* src = eidx;
    const int* dst = eidx + E;

    char* ws = (char*)d_ws;
    size_t off = 0;
    auto carve = [&](size_t bytes) -> void* {
        void* p = (void*)(ws + off);
        off = (off + bytes + 511) & ~(size_t)511;
        return p;
    };
    unsigned short* z      = (unsigned short*)carve((size_t)N * H * sizeof(unsigned short));
    unsigned short* hbf    = (unsigned short*)carve((size_t)N * H * sizeof(unsigned short));
    int*   sorted = (int*)carve((size_t)E * sizeof(int));
    int*   rowptr = (int*)carve((size_t)(N + 1) * sizeof(int));
    int*   deg    = (int*)carve((size_t)N * sizeof(int));
    int*   cursor = (int*)carve((size_t)N * sizeof(int));
    const int NB  = (N + 1023) / 1024;
    int*   bsum   = (int*)carve((size_t)NB * sizeof(int));
    unsigned short* el_tab = (unsigned short*)carve((size_t)LAYERS * NLBL * H * sizeof(unsigned short));
    float* e_proj = (float*)carve((size_t)NLBL * ED * sizeof(float));
    unsigned short* wsp = (unsigned short*)carve((size_t)7 * H * H * sizeof(unsigned short));
    float* h_out = (float*)d_out;

    // weight prep (bf16, transposed to [col][k])
    split_weights_kernel<<<dim3(64, 7), 256, 0, stream>>>(W_ref, W_a, W_b, wsp);

    // CSR build
    hipMemsetAsync(deg, 0, (size_t)N * sizeof(int), stream);
    hist_kernel<<<(E + 255) / 256, 256, 0, stream>>>(dst, E, deg);
    scan_block_sums<<<NB, 1024, 0, stream>>>(deg, N, bsum);
    scan_bsum<<<1, 64, 0, stream>>>(bsum, NB, rowptr + N);
    scan_final<<<NB, 1024, 0, stream>>>(deg, N, bsum, rowptr);
    hipMemsetAsync(cursor, 0, (size_t)N * sizeof(int), stream);
    scatter_kernel<<<(E + 255) / 256, 256, 0, stream>>>(src, dst, eattr, E, rowptr, cursor, sorted);

    // edge feature tables (256 labels only)
    edge_proj_kernel<<<NLBL, ED, 0, stream>>>(edge_emb, Pe1, be1, Pe2, be2, e_proj);
    el_tab_kernel<<<dim3(NLBL, LAYERS), H, 0, stream>>>(e_proj, W_lin, b_lin, el_tab);

    // node path
    const int gridMM = (N + 63) / 64;
    input_proj_mfma_kernel<<<gridMM, 128, 0, stream>>>(
        nf, W_in, b_in, wsp, b_ref, node_emb, N, hbf);

    for (int l = 0; l < LAYERS; ++l) {
        gather_kernel<<<(N + 3) / 4, 256, 0, stream>>>(
            hbf, rowptr, sorted, el_tab + (size_t)l * NLBL * H, N, z);
        mlp_mfma_kernel<<<gridMM, 128, 0, stream>>>(
            z,
            wsp + (size_t)(1 + l) * H * H, b_a + (size_t)l * H,
            wsp + (size_t)(4 + l) * H * H, b_b + (size_t)l * H,
            N, hbf, (l == LAYERS - 1) ? h_out : nullptr);
    }
}

// Round 5
// 482.015 us; speedup vs baseline: 2.8999x; 1.2598x over previous
//
#include <hip/hip_runtime.h>

#define H 128
#define ED 32
#define NLBL 256
#define NNODE_LBL 4096
#define LAYERS 3
#define SPAN 128          // nodes per bucket (dst >> 7); dstlocal fits 7 bits
#define MAXB 1024         // LDS cap for bucket arrays (nb = ceil(100000/128) = 782)

typedef short bf16x8 __attribute__((ext_vector_type(8)));
typedef float f32x4 __attribute__((ext_vector_type(4)));

#define TWO48F 281474976710655.0f

static __device__ __forceinline__ float relu_f(float x) { return fmaxf(x, 0.f); }

static __device__ __forceinline__ unsigned short f2bf(float x) {
    unsigned u = __float_as_uint(x);
    return (unsigned short)((u + 0x7fffu + ((u >> 16) & 1u)) >> 16);
}

static __device__ __forceinline__ float bf2f(short b) {
    return __uint_as_float(((unsigned)(unsigned short)b) << 16);
}

// ---------------- weight prep: fp32 [k][c] -> bf16 transposed [c][k] ----------------
// matrices: 0 = W_ref, 1..3 = W_a[l], 4..6 = W_b[l]

__global__ void split_weights_kernel(const float* __restrict__ W_ref,
                                     const float* __restrict__ W_a,
                                     const float* __restrict__ W_b,
                                     unsigned short* __restrict__ out) {
    int mat = blockIdx.y;
    const float* src = (mat == 0) ? W_ref
                     : (mat <= 3) ? W_a + (size_t)(mat - 1) * H * H
                                  : W_b + (size_t)(mat - 4) * H * H;
    int idx = blockIdx.x * 256 + threadIdx.x;      // [0, 16384)
    int k = idx >> 7, c = idx & 127;
    out[(size_t)mat * H * H + (size_t)c * H + k] = f2bf(src[idx]);
}

// ---------------- edge feature path (256 distinct labels only) ----------------

__global__ void edge_proj_kernel(const float* __restrict__ emb,
                                 const float* __restrict__ Pe1, const float* __restrict__ be1,
                                 const float* __restrict__ Pe2, const float* __restrict__ be2,
                                 float* __restrict__ e_proj) {
    int a = blockIdx.x, d = threadIdx.x;
    __shared__ float t[ED];
    float acc = be1[d];
    for (int k = 0; k < ED; ++k) acc = fmaf(emb[a * ED + k], Pe1[k * ED + d], acc);
    t[d] = fmaxf(acc, 0.f);
    __syncthreads();
    float acc2 = be2[d];
    for (int k = 0; k < ED; ++k) acc2 = fmaf(t[k], Pe2[k * ED + d], acc2);
    e_proj[a * ED + d] = acc2;
}

// el_tab in bf16 (gather consumes bf16)
__global__ void el_tab_kernel(const float* __restrict__ e_proj,
                              const float* __restrict__ W_lin, const float* __restrict__ b_lin,
                              unsigned short* __restrict__ el_tab) {
    int a = blockIdx.x, l = blockIdx.y, k = threadIdx.x;
    float acc = b_lin[l * H + k];
    for (int d = 0; d < ED; ++d)
        acc = fmaf(e_proj[a * ED + d], W_lin[(l * ED + d) * H + k], acc);
    el_tab[((size_t)l * NLBL + a) * H + k] = f2bf(acc);
}

// ---------------- CSR build: bucket hist -> scan -> block-owned partition -> place ------
// Eliminates cross-XCD partial-line write amplification: every written line belongs to
// one block (= one XCD) in one time window.

__global__ __launch_bounds__(256) void bucket_hist_kernel(
    const int* __restrict__ dst, int E, int nb, int* __restrict__ bcnt) {
    __shared__ int lh[MAXB];
    for (int i = threadIdx.x; i < nb; i += 256) lh[i] = 0;
    __syncthreads();
    for (int e = blockIdx.x * 256 + threadIdx.x; e < E; e += gridDim.x * 256)
        atomicAdd(&lh[dst[e] >> 7], 1);
    __syncthreads();
    for (int i = threadIdx.x; i < nb; i += 256)
        if (lh[i]) atomicAdd(&bcnt[i], lh[i]);
}

__global__ void bucket_scan_kernel(const int* __restrict__ bcnt, int nb,
                                   int* __restrict__ bbase, int* __restrict__ gcur) {
    __shared__ int s[MAXB];
    int t = threadIdx.x;                       // 1024 threads
    s[t] = (t < nb) ? bcnt[t] : 0;
    __syncthreads();
    for (int off = 1; off < MAXB; off <<= 1) {
        int v = (t >= off) ? s[t - off] : 0;
        __syncthreads();
        s[t] += v;
        __syncthreads();
    }
    if (t < nb) {
        int ex = (t == 0) ? 0 : s[t - 1];
        bbase[t] = ex;
        gcur[t] = ex;
    }
    if (t == nb) bbase[nb] = s[nb - 1];        // = E
}

// entry = src | attr<<17 | dstlocal<<25  (17 + 8 + 7 = 32 bits)
__global__ __launch_bounds__(256) void partition_kernel(
    const int* __restrict__ src, const int* __restrict__ dst,
    const int* __restrict__ attr, int E, int nb,
    int* __restrict__ gcur, unsigned* __restrict__ ebuf) {
    __shared__ int lh[MAXB], gofs[MAXB], lc[MAXB];
    const int t = threadIdx.x;
    const int e0 = blockIdx.x * 4096;
    const int e1 = min(e0 + 4096, E);
    for (int i = t; i < nb; i += 256) { lh[i] = 0; lc[i] = 0; }
    __syncthreads();
    for (int e = e0 + t; e < e1; e += 256) atomicAdd(&lh[dst[e] >> 7], 1);
    __syncthreads();
    for (int i = t; i < nb; i += 256)
        if (lh[i]) gofs[i] = atomicAdd(&gcur[i], lh[i]);
    __syncthreads();
    for (int e = e0 + t; e < e1; e += 256) {
        int d = dst[e];
        int b = d >> 7;
        int slot = gofs[b] + atomicAdd(&lc[b], 1);
        ebuf[slot] = (unsigned)src[e] | ((unsigned)attr[e] << 17) | ((unsigned)(d & 127) << 25);
    }
}

// one block per bucket: local count + scan -> rowptr, then place into 8KB private window
__global__ __launch_bounds__(128) void place_kernel(
    const unsigned* __restrict__ ebuf, const int* __restrict__ bbase,
    int n, int nb, int* __restrict__ rowptr, int* __restrict__ sorted) {
    __shared__ int lofs[SPAN], lc[SPAN];
    const int b = blockIdx.x;
    const int t = threadIdx.x;                 // 128
    const int base = bbase[b], endp = bbase[b + 1];
    lc[t] = 0;
    __syncthreads();
    for (int e = base + t; e < endp; e += 128)
        atomicAdd(&lc[ebuf[e] >> 25], 1);
    __syncthreads();
    int v = lc[t];
    lofs[t] = v;
    __syncthreads();
    for (int off = 1; off < SPAN; off <<= 1) {
        int add = (t >= off) ? lofs[t - off] : 0;
        __syncthreads();
        lofs[t] += add;
        __syncthreads();
    }
    int inc = lofs[t];
    __syncthreads();
    lofs[t] = inc - v;                          // exclusive
    lc[t] = 0;
    int node = b * SPAN + t;
    if (node < n) rowptr[node] = base + inc - v;
    if (b == 0 && t == 0) rowptr[n] = bbase[nb];
    __syncthreads();
    for (int e = base + t; e < endp; e += 128) {
        unsigned p = ebuf[e];
        int dl = p >> 25;
        int pos = base + lofs[dl] + atomicAdd(&lc[dl], 1);
        sorted[pos] = (int)(p & 0x1FFFFFFu);
    }
}

// ---------------- per-node aggregation: z = h + sum relu(h[src] + el[attr]) ----------------
// bf16 h/el/z. One wave per node; 4 edges in flight (4 groups x 16 lanes x 16B);
// fp32 accumulate; cross-group shfl_xor reduce; 16-lane bf16x8 z store.

__global__ __launch_bounds__(256) void gather_kernel(
    const unsigned short* __restrict__ hbf, const int* __restrict__ rowptr,
    const int* __restrict__ sorted, const unsigned short* __restrict__ el,
    int n, unsigned short* __restrict__ z) {
    int wave = threadIdx.x >> 6;
    int lane = threadIdx.x & 63;
    int i = blockIdx.x * 4 + wave;
    if (i >= n) return;
    int beg = rowptr[i], end = rowptr[i + 1];
    int gg = lane >> 4, m = lane & 15;
    float acc[8];
#pragma unroll
    for (int j = 0; j < 8; ++j) acc[j] = 0.f;
    for (int e = beg; e < end; e += 4) {
        int idx = e + gg;
        int p = (idx < end) ? sorted[idx] : -1;
        if (p >= 0) {
            int s = p & 131071;
            int a = p >> 17;
            bf16x8 hv = *(const bf16x8*)(hbf + (size_t)s * H + m * 8);
            bf16x8 ev = *(const bf16x8*)(el + (size_t)a * H + m * 8);
#pragma unroll
            for (int j = 0; j < 8; ++j)
                acc[j] += fmaxf(bf2f(hv[j]) + bf2f(ev[j]), 0.f);
        }
    }
#pragma unroll
    for (int j = 0; j < 8; ++j) {
        acc[j] += __shfl_xor(acc[j], 16, 64);
        acc[j] += __shfl_xor(acc[j], 32, 64);
    }
    if (gg == 0) {
        bf16x8 hv = *(const bf16x8*)(hbf + (size_t)i * H + m * 8);
        bf16x8 o;
#pragma unroll
        for (int j = 0; j < 8; ++j)
            o[j] = (short)f2bf(bf2f(hv[j]) + acc[j]);
        *(bf16x8*)(z + (size_t)i * H + m * 8) = o;
    }
}

// ---------------- MFMA fused MLP: h = relu(relu(z@Wa+ba)@Wb+bb), bf16 in, bf16/fp32 out ----
// 2 waves/block, 32 nodes/wave. T staged per-wave in LDS bf16 with XOR swizzle
// k' = k ^ 8*(node&7). Weights read as B-frags from pre-transposed global [col][k].
// All frag-array indices compile-time (rule #20).

__global__ __launch_bounds__(128) void mlp_mfma_kernel(
    const unsigned short* __restrict__ z,
    const unsigned short* __restrict__ WA, const float* __restrict__ ba,
    const unsigned short* __restrict__ WB, const float* __restrict__ bb,
    int n, unsigned short* __restrict__ hbf, float* __restrict__ hf32) {
    __shared__ short sT[2][32 * H];
    const int t = threadIdx.x;
    const int w = t >> 6, lane = t & 63;
    const int m = lane & 15, g = lane >> 4;
    const int nb = blockIdx.x * 64 + w * 32;

    // ---- load z fragments (direct bf16); A-frag: lane holds row m, k = 32ks+8g..+8 ----
    bf16x8 za[2][4];
#pragma unroll
    for (int rt = 0; rt < 2; ++rt) {
        int row = nb + 16 * rt + m; if (row >= n) row = n - 1;
        const unsigned short* zr = z + (size_t)row * H;
#pragma unroll
        for (int ks = 0; ks < 4; ++ks)
            za[rt][ks] = *(const bf16x8*)(zr + 32 * ks + 8 * g);
    }

    // ---- matmul1: T = relu(z@Wa + ba) -> LDS ----
#pragma unroll 1
    for (int ct = 0; ct < 8; ++ct) {
        float bias = ba[16 * ct + m];
        f32x4 c1[2];
        c1[0] = (f32x4){bias, bias, bias, bias};
        c1[1] = c1[0];
#pragma unroll
        for (int ks = 0; ks < 4; ++ks) {
            bf16x8 bh = *(const bf16x8*)(WA + (size_t)(16 * ct + m) * H + 32 * ks + 8 * g);
            c1[0] = __builtin_amdgcn_mfma_f32_16x16x32_bf16(za[0][ks], bh, c1[0], 0, 0, 0);
            c1[1] = __builtin_amdgcn_mfma_f32_16x16x32_bf16(za[1][ks], bh, c1[1], 0, 0, 0);
        }
        // C-frag: row(node) = 4g+r, col = 16ct+m; write relu(T) swizzled
#pragma unroll
        for (int rt = 0; rt < 2; ++rt) {
#pragma unroll
            for (int r = 0; r < 4; ++r) {
                float v = fmaxf(c1[rt][r], 0.f);
                int nl = 16 * rt + 4 * g + r;
                int kk = (16 * ct + m) ^ (8 * (nl & 7));
                sT[w][nl * H + kk] = (short)f2bf(v);
            }
        }
    }

    __syncthreads();

    // ---- matmul2: out = relu(T@Wb + bb) ----
    f32x4 c2[2][8];
#pragma unroll
    for (int ct = 0; ct < 8; ++ct) {
        float bias = bb[16 * ct + m];
        c2[0][ct] = (f32x4){bias, bias, bias, bias};
        c2[1][ct] = c2[0][ct];
    }
#pragma unroll 1
    for (int ks = 0; ks < 4; ++ks) {
        bf16x8 ta[2];
#pragma unroll
        for (int rt = 0; rt < 2; ++rt) {
            int nl = 16 * rt + m;
            int kk = (32 * ks + 8 * g) ^ (8 * (nl & 7));
            ta[rt] = *(const bf16x8*)&sT[w][nl * H + kk];
        }
#pragma unroll
        for (int ct = 0; ct < 8; ++ct) {
            bf16x8 bh = *(const bf16x8*)(WB + (size_t)(16 * ct + m) * H + 32 * ks + 8 * g);
            c2[0][ct] = __builtin_amdgcn_mfma_f32_16x16x32_bf16(ta[0], bh, c2[0][ct], 0, 0, 0);
            c2[1][ct] = __builtin_amdgcn_mfma_f32_16x16x32_bf16(ta[1], bh, c2[1][ct], 0, 0, 0);
        }
    }

    // ---- epilogue: intermediate layers -> bf16 h; final layer -> fp32 d_out ----
    if (hf32) {
#pragma unroll
        for (int rt = 0; rt < 2; ++rt)
#pragma unroll
            for (int r = 0; r < 4; ++r) {
                int node = nb + 16 * rt + 4 * g + r;
                if (node < n) {
                    float* hp = hf32 + (size_t)node * H + m;
#pragma unroll
                    for (int ct = 0; ct < 8; ++ct)
                        hp[16 * ct] = fmaxf(c2[rt][ct][r], 0.f);
                }
            }
    } else {
#pragma unroll
        for (int rt = 0; rt < 2; ++rt)
#pragma unroll
            for (int r = 0; r < 4; ++r) {
                int node = nb + 16 * rt + 4 * g + r;
                if (node < n) {
                    unsigned short* hp = hbf + (size_t)node * H + m;
#pragma unroll
                    for (int ct = 0; ct < 8; ++ct)
                        hp[16 * ct] = f2bf(fmaxf(c2[rt][ct][r], 0.f));
                }
            }
    }
}

// ---------------- input proj (rank-1 first layer) + refine matmul + node emb, MFMA ----------------
// h = (relu(x*W_in + b_in) @ W_ref + b_ref) + node_emb[id]   (no outer relu), bf16 out

__global__ __launch_bounds__(128) void input_proj_mfma_kernel(
    const float* __restrict__ nf,
    const float* __restrict__ W_in, const float* __restrict__ b_in,
    const unsigned short* __restrict__ WR, const float* __restrict__ b_ref,
    const float* __restrict__ node_emb,
    int n, unsigned short* __restrict__ hbf) {
    __shared__ float sx[64];
    __shared__ int sid[64];
    const int t = threadIdx.x;
    const int w = t >> 6, lane = t & 63;
    const int m = lane & 15, g = lane >> 4;
    const int nb0 = blockIdx.x * 64;
    if (t < 64) {
        int node = nb0 + t;
        float xv = (node < n) ? nf[node] : 0.f;
        sx[t] = fminf(fmaxf(xv / TWO48F, 0.f), 1.f);
        sid[t] = ((int)xv) & (NNODE_LBL - 1);
    }
    __syncthreads();
    const int nb = nb0 + w * 32;

    // T0[node][k] = relu(x_node * W_in[k] + b_in[k]) computed directly into A-frags
    bf16x8 ta[2][4];
#pragma unroll
    for (int rt = 0; rt < 2; ++rt) {
        float xv = sx[w * 32 + 16 * rt + m];
#pragma unroll
        for (int ks = 0; ks < 4; ++ks) {
            float4 w0 = *(const float4*)(W_in + 32 * ks + 8 * g);
            float4 w1 = *(const float4*)(W_in + 32 * ks + 8 * g + 4);
            float4 b0 = *(const float4*)(b_in + 32 * ks + 8 * g);
            float4 b1 = *(const float4*)(b_in + 32 * ks + 8 * g + 4);
            bf16x8 v;
            v[0] = (short)f2bf(relu_f(fmaf(xv, w0.x, b0.x)));
            v[1] = (short)f2bf(relu_f(fmaf(xv, w0.y, b0.y)));
            v[2] = (short)f2bf(relu_f(fmaf(xv, w0.z, b0.z)));
            v[3] = (short)f2bf(relu_f(fmaf(xv, w0.w, b0.w)));
            v[4] = (short)f2bf(relu_f(fmaf(xv, w1.x, b1.x)));
            v[5] = (short)f2bf(relu_f(fmaf(xv, w1.y, b1.y)));
            v[6] = (short)f2bf(relu_f(fmaf(xv, w1.z, b1.z)));
            v[7] = (short)f2bf(relu_f(fmaf(xv, w1.w, b1.w)));
            ta[rt][ks] = v;
        }
    }

    f32x4 c2[2][8];
#pragma unroll
    for (int ct = 0; ct < 8; ++ct) {
        float bias = b_ref[16 * ct + m];
        c2[0][ct] = (f32x4){bias, bias, bias, bias};
        c2[1][ct] = c2[0][ct];
    }
#pragma unroll
    for (int ct = 0; ct < 8; ++ct) {
#pragma unroll
        for (int ks = 0; ks < 4; ++ks) {
            bf16x8 bh = *(const bf16x8*)(WR + (size_t)(16 * ct + m) * H + 32 * ks + 8 * g);
            c2[0][ct] = __builtin_amdgcn_mfma_f32_16x16x32_bf16(ta[0][ks], bh, c2[0][ct], 0, 0, 0);
            c2[1][ct] = __builtin_amdgcn_mfma_f32_16x16x32_bf16(ta[1][ks], bh, c2[1][ct], 0, 0, 0);
        }
    }

    // epilogue: + node_emb[id], NO outer relu, bf16 store
#pragma unroll
    for (int rt = 0; rt < 2; ++rt)
#pragma unroll
        for (int r = 0; r < 4; ++r) {
            int node = nb + 16 * rt + 4 * g + r;
            if (node < n) {
                int id = sid[w * 32 + 16 * rt + 4 * g + r];
                const float* ep = node_emb + (size_t)id * H + m;
                unsigned short* hp = hbf + (size_t)node * H + m;
#pragma unroll
                for (int ct = 0; ct < 8; ++ct)
                    hp[16 * ct] = f2bf(c2[rt][ct][r] + ep[16 * ct]);
            }
        }
}

// ---------------- host launcher ----------------

extern "C" void kernel_launch(void* const* d_in, const int* in_sizes, int n_in,
                              void* d_out, int out_size, void* d_ws, size_t ws_size,
                              hipStream_t stream) {
    const float* nf       = (const float*)d_in[0];
    const int*   eidx     = (const int*)d_in[1];
    const int*   eattr    = (const int*)d_in[2];
    const float* W_in     = (const float*)d_in[3];
    const float* b_in     = (const float*)d_in[4];
    const float* W_ref    = (const float*)d_in[5];
    const float* b_ref    = (const float*)d_in[6];
    const float* node_emb = (const float*)d_in[7];
    const float* edge_emb = (const float*)d_in[8];
    const float* Pe1      = (const float*)d_in[9];
    const float* be1      = (const float*)d_in[10];
    const float* Pe2      = (const float*)d_in[11];
    const float* be2      = (const float*)d_in[12];
    const float* W_lin    = (const float*)d_in[13];
    const float* b_lin    = (const float*)d_in[14];
    const float* W_a      = (const float*)d_in[15];
    const float* b_a      = (const float*)d_in[16];
    const float* W_b      = (const float*)d_in[17];
    const float* b_b      = (const float*)d_in[18];

    const int N = in_sizes[0];
    const int E = in_sizes[2];
    const int* src = eidx;
    const int* dst = eidx + E;
    const int nb = (N + SPAN - 1) / SPAN;     // 782 buckets

    char* ws = (char*)d_ws;
    size_t off = 0;
    auto carve = [&](size_t bytes) -> void* {
        void* p = (void*)(ws + off);
        off = (off + bytes + 511) & ~(size_t)511;
        return p;
    };
    unsigned short* z      = (unsigned short*)carve((size_t)N * H * sizeof(unsigned short));
    unsigned short* hbf    = (unsigned short*)carve((size_t)N * H * sizeof(unsigned short));
    unsigned* ebuf  = (unsigned*)carve((size_t)E * sizeof(unsigned));
    int*   sorted = (int*)carve((size_t)E * sizeof(int));
    int*   rowptr = (int*)carve((size_t)(N + 1) * sizeof(int));
    int*   bcnt   = (int*)carve((size_t)nb * sizeof(int));
    int*   bbase  = (int*)carve((size_t)(nb + 1) * sizeof(int));
    int*   gcur   = (int*)carve((size_t)nb * sizeof(int));
    unsigned short* el_tab = (unsigned short*)carve((size_t)LAYERS * NLBL * H * sizeof(unsigned short));
    float* e_proj = (float*)carve((size_t)NLBL * ED * sizeof(float));
    unsigned short* wsp = (unsigned short*)carve((size_t)7 * H * H * sizeof(unsigned short));
    float* h_out = (float*)d_out;

    // weight prep (bf16, transposed to [col][k])
    split_weights_kernel<<<dim3(64, 7), 256, 0, stream>>>(W_ref, W_a, W_b, wsp);

    // CSR build: bucket hist -> scan -> block-owned partition -> place
    hipMemsetAsync(bcnt, 0, (size_t)nb * sizeof(int), stream);
    bucket_hist_kernel<<<512, 256, 0, stream>>>(dst, E, nb, bcnt);
    bucket_scan_kernel<<<1, MAXB, 0, stream>>>(bcnt, nb, bbase, gcur);
    partition_kernel<<<(E + 4095) / 4096, 256, 0, stream>>>(src, dst, eattr, E, nb, gcur, ebuf);
    place_kernel<<<nb, SPAN, 0, stream>>>(ebuf, bbase, N, nb, rowptr, sorted);

    // edge feature tables (256 labels only)
    edge_proj_kernel<<<NLBL, ED, 0, stream>>>(edge_emb, Pe1, be1, Pe2, be2, e_proj);
    el_tab_kernel<<<dim3(NLBL, LAYERS), H, 0, stream>>>(e_proj, W_lin, b_lin, el_tab);

    // node path
    const int gridMM = (N + 63) / 64;
    input_proj_mfma_kernel<<<gridMM, 128, 0, stream>>>(
        nf, W_in, b_in, wsp, b_ref, node_emb, N, hbf);

    for (int l = 0; l < LAYERS; ++l) {
        gather_kernel<<<(N + 3) / 4, 256, 0, stream>>>(
            hbf, rowptr, sorted, el_tab + (size_t)l * NLBL * H, N, z);
        mlp_mfma_kernel<<<gridMM, 128, 0, stream>>>(
            z,
            wsp + (size_t)(1 + l) * H * H, b_a + (size_t)l * H,
            wsp + (size_t)(4 + l) * H * H, b_b + (size_t)l * H,
            N, hbf, (l == LAYERS - 1) ? h_out : nullptr);
    }
}